// Round 1
// baseline (7102.583 us; speedup 1.0000x reference)
//
#include <hip/hip_runtime.h>
#include <math.h>

#define BATCH 8
#define SEQ 512
#define NVAR 1024
#define DM 512
#define NH 8
#define DH 64
#define NE 8
#define NF 8
#define NL 2
#define NTOK (BATCH*NVAR)   // 8192
#define LN_EPS 1e-5f

// ---------------------------------------------------------------- RevIN stats
// mean/std per (b, n) over the S(time) axis.  x is [B, S, N].
__global__ __launch_bounds__(256) void revin_stats_kernel(
        const float* __restrict__ x, float* __restrict__ mean, float* __restrict__ stdd) {
    int blk = blockIdx.x;            // b*16 + ntile
    int b = blk >> 4;
    int n0 = (blk & 15) << 6;
    int t = threadIdx.x;
    int ni = t & 63, sg = t >> 6;    // sg: 0..3
    float s = 0.f, ss = 0.f;
    for (int sidx = sg; sidx < SEQ; sidx += 4) {
        float v = x[((size_t)b*SEQ + sidx)*NVAR + n0 + ni];
        s += v; ss += v*v;
    }
    __shared__ float rs[4][64], rq[4][64];
    rs[sg][ni] = s; rq[sg][ni] = ss;
    __syncthreads();
    if (t < 64) {
        float su = rs[0][t] + rs[1][t] + rs[2][t] + rs[3][t];
        float sq = rq[0][t] + rq[1][t] + rq[2][t] + rq[3][t];
        float m  = su / (float)SEQ;
        float var = sq / (float)SEQ - m*m;
        int n = n0 + t;
        mean[b*NVAR + n] = m;
        stdd[b*NVAR + n] = sqrtf(var + LN_EPS);
    }
}

// ------------------------------------------------- RevIN normalize + transpose
// xn[b, n, s] = (x[b, s, n] - mean) / std * rw[n] + rb[n]
__global__ __launch_bounds__(256) void revin_norm_kernel(
        const float* __restrict__ x, const float* __restrict__ mean, const float* __restrict__ stdd,
        const float* __restrict__ rw, const float* __restrict__ rb, float* __restrict__ xn) {
    __shared__ float tile[32][33];
    int n0 = blockIdx.x << 5, s0 = blockIdx.y << 5, b = blockIdx.z;
    int t = threadIdx.x;
    int j = t & 31, i0 = t >> 5;     // i0: 0..7
    for (int ii = i0; ii < 32; ii += 8)
        tile[ii][j] = x[((size_t)b*SEQ + s0 + ii)*NVAR + n0 + j];
    __syncthreads();
    int si = t & 31, j0 = t >> 5;
    for (int nj = j0; nj < 32; nj += 8) {
        int n = n0 + nj;
        float m = mean[b*NVAR + n], sd = stdd[b*NVAR + n];
        xn[((size_t)b*NVAR + n)*SEQ + s0 + si] = (tile[si][nj] - m) / sd * rw[n] + rb[n];
    }
}

// ---------------------------------------------------------------- fp32 GEMM
// C[M,N] = A[M,K] @ W[K,N] + bias[N].  BM=BN=64, BK=16, 256 thr, 4x4 microtile.
__global__ __launch_bounds__(256) void gemm_bias_kernel(
        const float* __restrict__ A, const float* __restrict__ W,
        const float* __restrict__ bias, float* __restrict__ C, int M, int K, int N) {
    __shared__ float As[16][65];
    __shared__ float Bs[16][64];
    int bm = blockIdx.y << 6, bn = blockIdx.x << 6;
    int t = threadIdx.x;
    int tx = t & 15, ty = t >> 4;
    int arow = t >> 4, acol = t & 15;
    int bcol = t & 63, brow = t >> 6;
    float acc[4][4] = {};
    for (int k0 = 0; k0 < K; k0 += 16) {
#pragma unroll
        for (int r = 0; r < 4; ++r)
            As[acol][arow + 16*r] = A[(size_t)(bm + arow + 16*r)*K + k0 + acol];
#pragma unroll
        for (int r = 0; r < 4; ++r)
            Bs[brow + 4*r][bcol] = W[(size_t)(k0 + brow + 4*r)*N + bn + bcol];
        __syncthreads();
#pragma unroll
        for (int kk = 0; kk < 16; ++kk) {
            float a0 = As[kk][ty*4+0], a1 = As[kk][ty*4+1];
            float a2 = As[kk][ty*4+2], a3 = As[kk][ty*4+3];
            float b0 = Bs[kk][tx*4+0], b1 = Bs[kk][tx*4+1];
            float b2 = Bs[kk][tx*4+2], b3 = Bs[kk][tx*4+3];
            acc[0][0] += a0*b0; acc[0][1] += a0*b1; acc[0][2] += a0*b2; acc[0][3] += a0*b3;
            acc[1][0] += a1*b0; acc[1][1] += a1*b1; acc[1][2] += a1*b2; acc[1][3] += a1*b3;
            acc[2][0] += a2*b0; acc[2][1] += a2*b1; acc[2][2] += a2*b2; acc[2][3] += a2*b3;
            acc[3][0] += a3*b0; acc[3][1] += a3*b1; acc[3][2] += a3*b2; acc[3][3] += a3*b3;
        }
        __syncthreads();
    }
#pragma unroll
    for (int i = 0; i < 4; ++i) {
        size_t row = bm + ty*4 + i;
#pragma unroll
        for (int jj = 0; jj < 4; ++jj) {
            int col = bn + tx*4 + jj;
            C[row*N + col] = acc[i][jj] + bias[col];
        }
    }
}

// ---------------------------------------------------------------- attention
// Fused softmax(Q Kt / 8) V per (b, h), 8 query rows per block.
__global__ __launch_bounds__(256) void attn_kernel(
        const float* __restrict__ q, const float* __restrict__ k,
        const float* __restrict__ v, float* __restrict__ o) {
    __shared__ float qs[8][64];
    __shared__ float pl[8][1024];
    __shared__ float red[8][32];
    __shared__ float ored[4][8][64];
    __shared__ float denom[8];
    int blk = blockIdx.x;
    int qb = blk & 127, bh = blk >> 7;
    int b = bh >> 3, hh = bh & 7;
    int q0 = qb << 3;
    int t = threadIdx.x;
    size_t headoff = (size_t)hh * DH;
    size_t bbase = (size_t)b * NVAR;

    for (int idx = t; idx < 512; idx += 256) {
        int r = idx >> 6, j = idx & 63;
        qs[r][j] = q[(bbase + q0 + r)*DM + headoff + j];
    }
    __syncthreads();

    // phase 1: logits
    for (int mi = 0; mi < 4; ++mi) {
        int m = mi*256 + t;
        const float4* kp = (const float4*)(k + (bbase + m)*DM + headoff);
        float acc[8] = {0,0,0,0,0,0,0,0};
        for (int c = 0; c < 16; ++c) {
            float4 kv = kp[c];
#pragma unroll
            for (int r = 0; r < 8; ++r) {
                float4 qv = *(const float4*)&qs[r][c*4];
                acc[r] += kv.x*qv.x + kv.y*qv.y + kv.z*qv.z + kv.w*qv.w;
            }
        }
#pragma unroll
        for (int r = 0; r < 8; ++r) pl[r][m] = acc[r] * 0.125f;
    }
    __syncthreads();

    // phase 2: softmax per row
    int row = t >> 5, l32 = t & 31;
    float mx = -1e30f;
    for (int m = l32; m < 1024; m += 32) mx = fmaxf(mx, pl[row][m]);
    red[row][l32] = mx;
    __syncthreads();
    float rmax = red[row][0];
#pragma unroll
    for (int i = 1; i < 32; ++i) rmax = fmaxf(rmax, red[row][i]);
    __syncthreads();
    float sm = 0.f;
    for (int m = l32; m < 1024; m += 32) {
        float ev = expf(pl[row][m] - rmax);
        pl[row][m] = ev; sm += ev;
    }
    red[row][l32] = sm;
    __syncthreads();
    if (l32 == 0) {
        float dsum = 0.f;
        for (int i = 0; i < 32; ++i) dsum += red[row][i];
        denom[row] = dsum;
    }
    __syncthreads();

    // phase 3: P @ V
    int j = t & 63, rq = t >> 6;
    float acc[8] = {0,0,0,0,0,0,0,0};
    for (int m = rq; m < 1024; m += 4) {
        float pv = v[(bbase + m)*DM + headoff + j];
#pragma unroll
        for (int r = 0; r < 8; ++r) acc[r] += pl[r][m] * pv;
    }
#pragma unroll
    for (int r = 0; r < 8; ++r) ored[rq][r][j] = acc[r];
    __syncthreads();
    for (int idx = t; idx < 512; idx += 256) {
        int r = idx >> 6, jj = idx & 63;
        float sv = ored[0][r][jj] + ored[1][r][jj] + ored[2][r][jj] + ored[3][r][jj];
        o[(bbase + q0 + r)*DM + headoff + jj] = sv / denom[r];
    }
}

// ---------------------------------------------------------------- LayerNorm
// h = LN(h + res) * w + b   (res nullable).  One block per token row, d=512.
__global__ __launch_bounds__(256) void ln_kernel(
        float* __restrict__ h, const float* __restrict__ res,
        const float* __restrict__ w, const float* __restrict__ b) {
    int rowi = blockIdx.x, t = threadIdx.x;
    size_t base = (size_t)rowi * DM;
    float v0 = h[base + t], v1 = h[base + t + 256];
    if (res) { v0 += res[base + t]; v1 += res[base + t + 256]; }
    __shared__ float rs[256], rq[256];
    rs[t] = v0 + v1; rq[t] = v0*v0 + v1*v1;
    __syncthreads();
    for (int off = 128; off > 0; off >>= 1) {
        if (t < off) { rs[t] += rs[t+off]; rq[t] += rq[t+off]; }
        __syncthreads();
    }
    float m = rs[0] / (float)DM;
    float var = rq[0] / (float)DM - m*m;
    float inv = 1.0f / sqrtf(var + LN_EPS);
    h[base + t]       = (v0 - m)*inv * w[t]       + b[t];
    h[base + t + 256] = (v1 - m)*inv * w[t + 256] + b[t + 256];
}

__device__ __forceinline__ float gelu_exact(float xv) {
    return 0.5f * xv * (1.0f + erff(xv * 0.70710678118654752f));
}

// ---------------------------------------------------------------- MoE FFN
// One block per token.  E=8, f=8, top-2.
__global__ __launch_bounds__(256) void moe_kernel(
        const float* __restrict__ h, float* __restrict__ out,
        const float* __restrict__ gW, const float* __restrict__ W1, const float* __restrict__ b1,
        const float* __restrict__ W2, const float* __restrict__ b2) {
    int tok = blockIdx.x, t = threadIdx.x;
    __shared__ float hs[DM];
    __shared__ float red[32][8];
    __shared__ float glog[8];
    __shared__ float hmid[8];
    __shared__ float wsel[2];
    __shared__ int   esel[2];
    size_t base = (size_t)tok * DM;
    hs[t] = h[base + t]; hs[t + 256] = h[base + t + 256];
    __syncthreads();
    int e = t & 7, i0 = t >> 3;
    {
        float a = 0.f;
        for (int i = i0; i < DM; i += 32) a += hs[i] * gW[i*NE + e];
        red[i0][e] = a;
    }
    __syncthreads();
    if (t < 8) { float sv = 0.f; for (int i = 0; i < 32; ++i) sv += red[i][t]; glog[t] = sv; }
    __syncthreads();
    if (t == 0) {
        float m0 = -1e30f, m1 = -1e30f; int s0i = 0, s1i = 0;
        for (int ei = 0; ei < 8; ++ei) {
            float vv = glog[ei];
            if (vv > m0) { m1 = m0; s1i = s0i; m0 = vv; s0i = ei; }
            else if (vv > m1) { m1 = vv; s1i = ei; }
        }
        float Z = 0.f;
        for (int ei = 0; ei < 8; ++ei) Z += expf(glog[ei] - m0);
        wsel[0] = 1.0f / Z;
        wsel[1] = expf(m1 - m0) / Z;
        esel[0] = s0i; esel[1] = s1i;
    }
    __syncthreads();
    float o0 = 0.f, o1 = 0.f;
    for (int ks = 0; ks < 2; ++ks) {
        int ee = esel[ks]; float wk = wsel[ks];
        int f = t & 7;
        float a = 0.f;
        for (int i = i0; i < DM; i += 32) a += hs[i] * W1[((size_t)ee*DM + i)*NF + f];
        red[i0][f] = a;
        __syncthreads();
        if (t < 8) {
            float sv = b1[ee*NF + t];
            for (int i = 0; i < 32; ++i) sv += red[i][t];
            hmid[t] = gelu_exact(sv);
        }
        __syncthreads();
        float s0v = b2[ee*DM + t], s1v = b2[ee*DM + t + 256];
#pragma unroll
        for (int i = 0; i < NF; ++i) {
            float hm = hmid[i];
            const float* wp = W2 + ((size_t)ee*NF + i)*DM;
            s0v += hm * wp[t]; s1v += hm * wp[t + 256];
        }
        o0 += wk * s0v; o1 += wk * s1v;
        __syncthreads();
    }
    out[base + t] = o0; out[base + t + 256] = o1;
}

// ---------------------------------------------------------------- MoE head + denorm
__global__ __launch_bounds__(256) void head_kernel(
        const float* __restrict__ h, const float* __restrict__ gW,
        const float* __restrict__ HW, const float* __restrict__ Hb,
        const float* __restrict__ rw, const float* __restrict__ rb,
        const float* __restrict__ mean, const float* __restrict__ stdd,
        float* __restrict__ out) {
    int tok = blockIdx.x, t = threadIdx.x;
    int n = tok & (NVAR - 1);
    __shared__ float hs[DM];
    __shared__ float red[32][8];
    __shared__ float glog[8];
    __shared__ float wsel[2];
    __shared__ int   esel[2];
    size_t base = (size_t)tok * DM;
    hs[t] = h[base + t]; hs[t + 256] = h[base + t + 256];
    __syncthreads();
    int e = t & 7, i0 = t >> 3;
    {
        float a = 0.f;
        for (int i = i0; i < DM; i += 32) a += hs[i] * gW[i*NE + e];
        red[i0][e] = a;
    }
    __syncthreads();
    if (t < 8) { float sv = 0.f; for (int i = 0; i < 32; ++i) sv += red[i][t]; glog[t] = sv; }
    __syncthreads();
    if (t == 0) {
        float m0 = -1e30f, m1 = -1e30f; int s0i = 0, s1i = 0;
        for (int ei = 0; ei < 8; ++ei) {
            float vv = glog[ei];
            if (vv > m0) { m1 = m0; s1i = s0i; m0 = vv; s0i = ei; }
            else if (vv > m1) { m1 = vv; s1i = ei; }
        }
        float Z = 0.f;
        for (int ei = 0; ei < 8; ++ei) Z += expf(glog[ei] - m0);
        wsel[0] = 1.0f / Z;
        wsel[1] = expf(m1 - m0) / Z;
        esel[0] = s0i; esel[1] = s1i;
    }
    __syncthreads();
    float o0 = 0.f, o1 = 0.f;
    for (int ks = 0; ks < 2; ++ks) {
        int ee = esel[ks]; float wk = wsel[ks];
        float s0v = Hb[ee*DM + t], s1v = Hb[ee*DM + t + 256];
        const float* wbase = HW + (size_t)ee*DM*DM;
        for (int i = 0; i < DM; i += 4) {
            float4 hv = *(const float4*)&hs[i];
            const float* wp = wbase + (size_t)i*DM;
            s0v += hv.x*wp[t]       + hv.y*wp[DM + t]       + hv.z*wp[2*DM + t]       + hv.w*wp[3*DM + t];
            s1v += hv.x*wp[t + 256] + hv.y*wp[DM + t + 256] + hv.z*wp[2*DM + t + 256] + hv.w*wp[3*DM + t + 256];
        }
        o0 += wk * s0v; o1 += wk * s1v;
    }
    float mn = mean[tok], sd = stdd[tok];
    float rwv = rw[n] + 1e-10f, rbv = rb[n];
    out[base + t]       = (o0 - rbv) / rwv * sd + mn;
    out[base + t + 256] = (o1 - rbv) / rwv * sd + mn;
}

// ---------------------------------------------------------------- launch
extern "C" void kernel_launch(void* const* d_in, const int* in_sizes, int n_in,
                              void* d_out, int out_size, void* d_ws, size_t ws_size,
                              hipStream_t stream) {
    const float* x       = (const float*)d_in[0];
    const float* revin_w = (const float*)d_in[1];
    const float* revin_b = (const float*)d_in[2];
    const float* emb_W   = (const float*)d_in[3];
    const float* emb_b   = (const float*)d_in[4];
    const float* Wq      = (const float*)d_in[5];
    const float* bq      = (const float*)d_in[6];
    const float* Wk      = (const float*)d_in[7];
    const float* bk      = (const float*)d_in[8];
    const float* Wv      = (const float*)d_in[9];
    const float* bv      = (const float*)d_in[10];
    const float* Wo      = (const float*)d_in[11];
    const float* bo      = (const float*)d_in[12];
    const float* ln1_w   = (const float*)d_in[13];
    const float* ln1_b   = (const float*)d_in[14];
    const float* ln2_w   = (const float*)d_in[15];
    const float* ln2_b   = (const float*)d_in[16];
    const float* gate_W  = (const float*)d_in[17];
    const float* eW1     = (const float*)d_in[18];
    const float* eb1     = (const float*)d_in[19];
    const float* eW2     = (const float*)d_in[20];
    const float* eb2     = (const float*)d_in[21];
    const float* enc_w   = (const float*)d_in[22];
    const float* enc_b   = (const float*)d_in[23];
    const float* hgW     = (const float*)d_in[24];
    const float* hW      = (const float*)d_in[25];
    const float* hb      = (const float*)d_in[26];
    float* out = (float*)d_out;

    const size_t TOKD = (size_t)NTOK * DM;   // 4194304
    float* ws   = (float*)d_ws;
    float* mean = ws;                // 8192
    float* stdd = ws + 8192;         // 8192
    float* xn   = ws + 16384;        // also attention output buffer
    float* h    = xn + TOKD;
    float* qb   = h + TOKD;
    float* kb   = qb + TOKD;
    float* vb   = kb + TOKD;
    float* ao   = xn;                // reuse after embedding
    float* proj = kb;                // reuse: K dead after attention

    dim3 blk(256);
    dim3 ggemm(DM/64, NTOK/64);      // (8, 128)

    revin_stats_kernel<<<dim3(BATCH*16), blk, 0, stream>>>(x, mean, stdd);
    revin_norm_kernel<<<dim3(NVAR/32, SEQ/32, BATCH), blk, 0, stream>>>(
        x, mean, stdd, revin_w, revin_b, xn);
    gemm_bias_kernel<<<ggemm, blk, 0, stream>>>(xn, emb_W, emb_b, h, NTOK, SEQ, DM);

    for (int l = 0; l < NL; ++l) {
        const float* wq = Wq + (size_t)l*DM*DM;
        const float* wk = Wk + (size_t)l*DM*DM;
        const float* wv = Wv + (size_t)l*DM*DM;
        const float* wo = Wo + (size_t)l*DM*DM;
        gemm_bias_kernel<<<ggemm, blk, 0, stream>>>(h, wq, bq + l*DM, qb, NTOK, DM, DM);
        gemm_bias_kernel<<<ggemm, blk, 0, stream>>>(h, wk, bk + l*DM, kb, NTOK, DM, DM);
        gemm_bias_kernel<<<ggemm, blk, 0, stream>>>(h, wv, bv + l*DM, vb, NTOK, DM, DM);
        attn_kernel<<<dim3(BATCH*NH*(NVAR/8)), blk, 0, stream>>>(qb, kb, vb, ao);
        gemm_bias_kernel<<<ggemm, blk, 0, stream>>>(ao, wo, bo + l*DM, proj, NTOK, DM, DM);
        ln_kernel<<<dim3(NTOK), blk, 0, stream>>>(h, proj, ln1_w + l*DM, ln1_b + l*DM);
        moe_kernel<<<dim3(NTOK), blk, 0, stream>>>(
            h, proj, gate_W + (size_t)l*DM*NE,
            eW1 + (size_t)l*NE*DM*NF, eb1 + (size_t)l*NE*NF,
            eW2 + (size_t)l*NE*NF*DM, eb2 + (size_t)l*NE*DM);
        ln_kernel<<<dim3(NTOK), blk, 0, stream>>>(h, proj, ln2_w + l*DM, ln2_b + l*DM);
    }

    ln_kernel<<<dim3(NTOK), blk, 0, stream>>>(h, nullptr, enc_w, enc_b);
    head_kernel<<<dim3(NTOK), blk, 0, stream>>>(
        h, hgW, hW, hb, revin_w, revin_b, mean, stdd, out);
}

// Round 2
// 2696.695 us; speedup vs baseline: 2.6338x; 2.6338x over previous
//
#include <hip/hip_runtime.h>
#include <math.h>

#define BATCH 8
#define SEQ 512
#define NVAR 1024
#define DM 512
#define NH 8
#define DH 64
#define NE 8
#define NF 8
#define NL 2
#define NTOK (BATCH*NVAR)   // 8192
#define LN_EPS 1e-5f

// ---------------------------------------------------------------- RevIN stats
__global__ __launch_bounds__(256) void revin_stats_kernel(
        const float* __restrict__ x, float* __restrict__ mean, float* __restrict__ stdd) {
    int blk = blockIdx.x;            // b*16 + ntile
    int b = blk >> 4;
    int n0 = (blk & 15) << 6;
    int t = threadIdx.x;
    int ni = t & 63, sg = t >> 6;
    float s = 0.f, ss = 0.f;
    for (int sidx = sg; sidx < SEQ; sidx += 4) {
        float v = x[((size_t)b*SEQ + sidx)*NVAR + n0 + ni];
        s += v; ss += v*v;
    }
    __shared__ float rs[4][64], rq[4][64];
    rs[sg][ni] = s; rq[sg][ni] = ss;
    __syncthreads();
    if (t < 64) {
        float su = rs[0][t] + rs[1][t] + rs[2][t] + rs[3][t];
        float sq = rq[0][t] + rq[1][t] + rq[2][t] + rq[3][t];
        float m  = su / (float)SEQ;
        float var = sq / (float)SEQ - m*m;
        int n = n0 + t;
        mean[b*NVAR + n] = m;
        stdd[b*NVAR + n] = sqrtf(var + LN_EPS);
    }
}

// ------------------------------------------------- RevIN normalize + transpose
__global__ __launch_bounds__(256) void revin_norm_kernel(
        const float* __restrict__ x, const float* __restrict__ mean, const float* __restrict__ stdd,
        const float* __restrict__ rw, const float* __restrict__ rb, float* __restrict__ xn) {
    __shared__ float tile[32][33];
    int n0 = blockIdx.x << 5, s0 = blockIdx.y << 5, b = blockIdx.z;
    int t = threadIdx.x;
    int j = t & 31, i0 = t >> 5;
    for (int ii = i0; ii < 32; ii += 8)
        tile[ii][j] = x[((size_t)b*SEQ + s0 + ii)*NVAR + n0 + j];
    __syncthreads();
    int si = t & 31, j0 = t >> 5;
    for (int nj = j0; nj < 32; nj += 8) {
        int n = n0 + nj;
        float m = mean[b*NVAR + n], sd = stdd[b*NVAR + n];
        xn[((size_t)b*NVAR + n)*SEQ + s0 + si] = (tile[si][nj] - m) / sd * rw[n] + rb[n];
    }
}

// ---------------------------------------------------------------- fp32 GEMM
__global__ __launch_bounds__(256) void gemm_bias_kernel(
        const float* __restrict__ A, const float* __restrict__ W,
        const float* __restrict__ bias, float* __restrict__ C, int M, int K, int N) {
    __shared__ float As[16][65];
    __shared__ float Bs[16][64];
    int bm = blockIdx.y << 6, bn = blockIdx.x << 6;
    int t = threadIdx.x;
    int tx = t & 15, ty = t >> 4;
    int arow = t >> 4, acol = t & 15;
    int bcol = t & 63, brow = t >> 6;
    float acc[4][4] = {};
    for (int k0 = 0; k0 < K; k0 += 16) {
#pragma unroll
        for (int r = 0; r < 4; ++r)
            As[acol][arow + 16*r] = A[(size_t)(bm + arow + 16*r)*K + k0 + acol];
#pragma unroll
        for (int r = 0; r < 4; ++r)
            Bs[brow + 4*r][bcol] = W[(size_t)(k0 + brow + 4*r)*N + bn + bcol];
        __syncthreads();
#pragma unroll
        for (int kk = 0; kk < 16; ++kk) {
            float a0 = As[kk][ty*4+0], a1 = As[kk][ty*4+1];
            float a2 = As[kk][ty*4+2], a3 = As[kk][ty*4+3];
            float b0 = Bs[kk][tx*4+0], b1 = Bs[kk][tx*4+1];
            float b2 = Bs[kk][tx*4+2], b3 = Bs[kk][tx*4+3];
            acc[0][0] += a0*b0; acc[0][1] += a0*b1; acc[0][2] += a0*b2; acc[0][3] += a0*b3;
            acc[1][0] += a1*b0; acc[1][1] += a1*b1; acc[1][2] += a1*b2; acc[1][3] += a1*b3;
            acc[2][0] += a2*b0; acc[2][1] += a2*b1; acc[2][2] += a2*b2; acc[2][3] += a2*b3;
            acc[3][0] += a3*b0; acc[3][1] += a3*b1; acc[3][2] += a3*b2; acc[3][3] += a3*b3;
        }
        __syncthreads();
    }
#pragma unroll
    for (int i = 0; i < 4; ++i) {
        size_t row = bm + ty*4 + i;
#pragma unroll
        for (int jj = 0; jj < 4; ++jj) {
            int col = bn + tx*4 + jj;
            C[row*N + col] = acc[i][jj] + bias[col];
        }
    }
}

// --------------------------------------------- K/V head-transpose (per layer)
// in:  [B*NVAR, DM] viewed [b][n][h][dh]
// out: [b*h][dh(64)][n(1024)]
__global__ __launch_bounds__(256) void transpose_kv_kernel(
        const float* __restrict__ in, float* __restrict__ outp) {
    __shared__ float tile[64][65];
    int blk = blockIdx.x;            // bh(64) * ntile(16)
    int bh = blk >> 4, n0 = (blk & 15) << 6;
    int b = bh >> 3, h = bh & 7;
    int t = threadIdx.x;
    int j = t & 63, i0 = t >> 6;
    for (int i = i0; i < 64; i += 4)
        tile[i][j] = in[((size_t)b*NVAR + n0 + i)*DM + h*DH + j];
    __syncthreads();
    int n = t & 63, c0 = t >> 6;
    for (int c = c0; c < 64; c += 4)
        outp[((size_t)bh*DH + c)*NVAR + n0 + n] = tile[n][c];
}

// ---------------------------------------------------------------- attention
// q:  [B*NVAR, DM]        (row-major, per-head slice)
// kt: [bh][64][1024]      (K transposed)
// vt: [bh][64][1024]      (V transposed)
// o:  [B*NVAR, DM]
// One block per (bh, 8-query-row tile).
__global__ __launch_bounds__(256) void attn_kernel(
        const float* __restrict__ q, const float* __restrict__ kt,
        const float* __restrict__ vt, float* __restrict__ o) {
    __shared__ float qs[8][64];
    __shared__ float pl[8][1024];
    __shared__ float red[8][32];
    __shared__ float denom[8];
    int blk = blockIdx.x;
    int qb = blk & 127, bh = blk >> 7;
    int b = bh >> 3, hh = bh & 7;
    int q0 = qb << 3;
    int t = threadIdx.x;
    size_t bbase = (size_t)b * NVAR;
    size_t kvbase = (size_t)bh * DH * NVAR;

    // stage Q (8 x 64)
    for (int idx = t; idx < 512; idx += 256) {
        int r = idx >> 6, j = idx & 63;
        qs[r][j] = q[(bbase + q0 + r)*DM + hh*DH + j];
    }
    __syncthreads();

    // phase 1: S = Q K^T.  Thread owns keys m0..m0+3 (coalesced kt loads).
    {
        int m0 = t << 2;
        float acc[8][4] = {};
#pragma unroll 4
        for (int c0 = 0; c0 < 64; c0 += 4) {
            float4 kv0 = *(const float4*)&kt[kvbase + (size_t)(c0+0)*NVAR + m0];
            float4 kv1 = *(const float4*)&kt[kvbase + (size_t)(c0+1)*NVAR + m0];
            float4 kv2 = *(const float4*)&kt[kvbase + (size_t)(c0+2)*NVAR + m0];
            float4 kv3 = *(const float4*)&kt[kvbase + (size_t)(c0+3)*NVAR + m0];
#pragma unroll
            for (int r = 0; r < 8; ++r) {
                float4 qv = *(const float4*)&qs[r][c0];
                acc[r][0] += qv.x*kv0.x + qv.y*kv1.x + qv.z*kv2.x + qv.w*kv3.x;
                acc[r][1] += qv.x*kv0.y + qv.y*kv1.y + qv.z*kv2.y + qv.w*kv3.y;
                acc[r][2] += qv.x*kv0.z + qv.y*kv1.z + qv.z*kv2.z + qv.w*kv3.z;
                acc[r][3] += qv.x*kv0.w + qv.y*kv1.w + qv.z*kv2.w + qv.w*kv3.w;
            }
        }
#pragma unroll
        for (int r = 0; r < 8; ++r) {
            float4 sv;
            sv.x = acc[r][0]*0.125f; sv.y = acc[r][1]*0.125f;
            sv.z = acc[r][2]*0.125f; sv.w = acc[r][3]*0.125f;
            *(float4*)&pl[r][m0] = sv;
        }
    }
    __syncthreads();

    // phase 2: softmax per row
    {
        int row = t >> 5, l32 = t & 31;
        float mx = -1e30f;
        for (int m = l32; m < 1024; m += 32) mx = fmaxf(mx, pl[row][m]);
        red[row][l32] = mx;
        __syncthreads();
        float rmax = red[row][0];
#pragma unroll
        for (int i = 1; i < 32; ++i) rmax = fmaxf(rmax, red[row][i]);
        __syncthreads();
        float sm = 0.f;
        for (int m = l32; m < 1024; m += 32) {
            float ev = __expf(pl[row][m] - rmax);
            pl[row][m] = ev; sm += ev;
        }
        red[row][l32] = sm;
        __syncthreads();
        if (l32 == 0) {
            float dsum = 0.f;
            for (int i = 0; i < 32; ++i) dsum += red[row][i];
            denom[row] = dsum;
        }
        __syncthreads();
    }

    // phase 3: O = P V.  Thread: mg(t&3) key-phase, jslot(bits2-4), mhalf(bit5),
    // wave(bits6-7).  Owns dims {j0, j0+8}, all 8 rows, keys m = mhalf*512 +
    // ch*16 + mg*4 + {0..3}.  vt loads are 64B-segment coalesced; pl reads are
    // aligned b128 (8 distinct 16B segs per wave -> conflict-free).
    {
        int mg = t & 3, jslot = (t >> 2) & 7, mhalf = (t >> 5) & 1, wv = t >> 6;
        int j0 = wv*16 + jslot, j1 = j0 + 8;
        const float* vtp0 = vt + kvbase + (size_t)j0*NVAR;
        const float* vtp1 = vt + kvbase + (size_t)j1*NVAR;
        float a0[8] = {}, a1[8] = {};
#pragma unroll 2
        for (int ch = 0; ch < 32; ++ch) {
            int m0 = mhalf*512 + ch*16 + mg*4;
            float4 vv0 = *(const float4*)&vtp0[m0];
            float4 vv1 = *(const float4*)&vtp1[m0];
#pragma unroll
            for (int r = 0; r < 8; ++r) {
                float4 pv = *(const float4*)&pl[r][m0];
                a0[r] += pv.x*vv0.x + pv.y*vv0.y + pv.z*vv0.z + pv.w*vv0.w;
                a1[r] += pv.x*vv1.x + pv.y*vv1.y + pv.z*vv1.z + pv.w*vv1.w;
            }
        }
        // butterfly-reduce partials over mg (bits 0,1) and mhalf (bit 5)
#pragma unroll
        for (int r = 0; r < 8; ++r) {
            a0[r] += __shfl_xor(a0[r], 1);  a1[r] += __shfl_xor(a1[r], 1);
            a0[r] += __shfl_xor(a0[r], 2);  a1[r] += __shfl_xor(a1[r], 2);
            a0[r] += __shfl_xor(a0[r], 32); a1[r] += __shfl_xor(a1[r], 32);
        }
        if (mg == 0 && mhalf == 0) {
#pragma unroll
            for (int r = 0; r < 8; ++r) {
                float inv = 1.0f / denom[r];
                size_t rowbase = (bbase + q0 + r)*DM + hh*DH;
                o[rowbase + j0] = a0[r] * inv;
                o[rowbase + j1] = a1[r] * inv;
            }
        }
    }
}

// ---------------------------------------------------------------- LayerNorm
__global__ __launch_bounds__(256) void ln_kernel(
        float* __restrict__ h, const float* __restrict__ res,
        const float* __restrict__ w, const float* __restrict__ b) {
    int rowi = blockIdx.x, t = threadIdx.x;
    size_t base = (size_t)rowi * DM;
    float v0 = h[base + t], v1 = h[base + t + 256];
    if (res) { v0 += res[base + t]; v1 += res[base + t + 256]; }
    __shared__ float rs[256], rq[256];
    rs[t] = v0 + v1; rq[t] = v0*v0 + v1*v1;
    __syncthreads();
    for (int off = 128; off > 0; off >>= 1) {
        if (t < off) { rs[t] += rs[t+off]; rq[t] += rq[t+off]; }
        __syncthreads();
    }
    float m = rs[0] / (float)DM;
    float var = rq[0] / (float)DM - m*m;
    float inv = 1.0f / sqrtf(var + LN_EPS);
    h[base + t]       = (v0 - m)*inv * w[t]       + b[t];
    h[base + t + 256] = (v1 - m)*inv * w[t + 256] + b[t + 256];
}

__device__ __forceinline__ float gelu_exact(float xv) {
    return 0.5f * xv * (1.0f + erff(xv * 0.70710678118654752f));
}

// ---------------------------------------------------------------- MoE FFN
__global__ __launch_bounds__(256) void moe_kernel(
        const float* __restrict__ h, float* __restrict__ out,
        const float* __restrict__ gW, const float* __restrict__ W1, const float* __restrict__ b1,
        const float* __restrict__ W2, const float* __restrict__ b2) {
    int tok = blockIdx.x, t = threadIdx.x;
    __shared__ float hs[DM];
    __shared__ float red[32][8];
    __shared__ float glog[8];
    __shared__ float hmid[8];
    __shared__ float wsel[2];
    __shared__ int   esel[2];
    size_t base = (size_t)tok * DM;
    hs[t] = h[base + t]; hs[t + 256] = h[base + t + 256];
    __syncthreads();
    int e = t & 7, i0 = t >> 3;
    {
        float a = 0.f;
        for (int i = i0; i < DM; i += 32) a += hs[i] * gW[i*NE + e];
        red[i0][e] = a;
    }
    __syncthreads();
    if (t < 8) { float sv = 0.f; for (int i = 0; i < 32; ++i) sv += red[i][t]; glog[t] = sv; }
    __syncthreads();
    if (t == 0) {
        float m0 = -1e30f, m1 = -1e30f; int s0i = 0, s1i = 0;
        for (int ei = 0; ei < 8; ++ei) {
            float vv = glog[ei];
            if (vv > m0) { m1 = m0; s1i = s0i; m0 = vv; s0i = ei; }
            else if (vv > m1) { m1 = vv; s1i = ei; }
        }
        float Z = 0.f;
        for (int ei = 0; ei < 8; ++ei) Z += expf(glog[ei] - m0);
        wsel[0] = 1.0f / Z;
        wsel[1] = expf(m1 - m0) / Z;
        esel[0] = s0i; esel[1] = s1i;
    }
    __syncthreads();
    float o0 = 0.f, o1 = 0.f;
    for (int ks = 0; ks < 2; ++ks) {
        int ee = esel[ks]; float wk = wsel[ks];
        int f = t & 7;
        float a = 0.f;
        for (int i = i0; i < DM; i += 32) a += hs[i] * W1[((size_t)ee*DM + i)*NF + f];
        red[i0][f] = a;
        __syncthreads();
        if (t < 8) {
            float sv = b1[ee*NF + t];
            for (int i = 0; i < 32; ++i) sv += red[i][t];
            hmid[t] = gelu_exact(sv);
        }
        __syncthreads();
        float s0v = b2[ee*DM + t], s1v = b2[ee*DM + t + 256];
#pragma unroll
        for (int i = 0; i < NF; ++i) {
            float hm = hmid[i];
            const float* wp = W2 + ((size_t)ee*NF + i)*DM;
            s0v += hm * wp[t]; s1v += hm * wp[t + 256];
        }
        o0 += wk * s0v; o1 += wk * s1v;
        __syncthreads();
    }
    out[base + t] = o0; out[base + t + 256] = o1;
}

// ---------------------------------------------------------------- MoE head + denorm
__global__ __launch_bounds__(256) void head_kernel(
        const float* __restrict__ h, const float* __restrict__ gW,
        const float* __restrict__ HW, const float* __restrict__ Hb,
        const float* __restrict__ rw, const float* __restrict__ rb,
        const float* __restrict__ mean, const float* __restrict__ stdd,
        float* __restrict__ out) {
    int tok = blockIdx.x, t = threadIdx.x;
    int n = tok & (NVAR - 1);
    __shared__ float hs[DM];
    __shared__ float red[32][8];
    __shared__ float glog[8];
    __shared__ float wsel[2];
    __shared__ int   esel[2];
    size_t base = (size_t)tok * DM;
    hs[t] = h[base + t]; hs[t + 256] = h[base + t + 256];
    __syncthreads();
    int e = t & 7, i0 = t >> 3;
    {
        float a = 0.f;
        for (int i = i0; i < DM; i += 32) a += hs[i] * gW[i*NE + e];
        red[i0][e] = a;
    }
    __syncthreads();
    if (t < 8) { float sv = 0.f; for (int i = 0; i < 32; ++i) sv += red[i][t]; glog[t] = sv; }
    __syncthreads();
    if (t == 0) {
        float m0 = -1e30f, m1 = -1e30f; int s0i = 0, s1i = 0;
        for (int ei = 0; ei < 8; ++ei) {
            float vv = glog[ei];
            if (vv > m0) { m1 = m0; s1i = s0i; m0 = vv; s0i = ei; }
            else if (vv > m1) { m1 = vv; s1i = ei; }
        }
        float Z = 0.f;
        for (int ei = 0; ei < 8; ++ei) Z += expf(glog[ei] - m0);
        wsel[0] = 1.0f / Z;
        wsel[1] = expf(m1 - m0) / Z;
        esel[0] = s0i; esel[1] = s1i;
    }
    __syncthreads();
    float o0 = 0.f, o1 = 0.f;
    for (int ks = 0; ks < 2; ++ks) {
        int ee = esel[ks]; float wk = wsel[ks];
        float s0v = Hb[ee*DM + t], s1v = Hb[ee*DM + t + 256];
        const float* wbase = HW + (size_t)ee*DM*DM;
        for (int i = 0; i < DM; i += 4) {
            float4 hv = *(const float4*)&hs[i];
            const float* wp = wbase + (size_t)i*DM;
            s0v += hv.x*wp[t]       + hv.y*wp[DM + t]       + hv.z*wp[2*DM + t]       + hv.w*wp[3*DM + t];
            s1v += hv.x*wp[t + 256] + hv.y*wp[DM + t + 256] + hv.z*wp[2*DM + t + 256] + hv.w*wp[3*DM + t + 256];
        }
        o0 += wk * s0v; o1 += wk * s1v;
    }
    float mn = mean[tok], sd = stdd[tok];
    float rwv = rw[n] + 1e-10f, rbv = rb[n];
    out[base + t]       = (o0 - rbv) / rwv * sd + mn;
    out[base + t + 256] = (o1 - rbv) / rwv * sd + mn;
}

// ---------------------------------------------------------------- launch
extern "C" void kernel_launch(void* const* d_in, const int* in_sizes, int n_in,
                              void* d_out, int out_size, void* d_ws, size_t ws_size,
                              hipStream_t stream) {
    const float* x       = (const float*)d_in[0];
    const float* revin_w = (const float*)d_in[1];
    const float* revin_b = (const float*)d_in[2];
    const float* emb_W   = (const float*)d_in[3];
    const float* emb_b   = (const float*)d_in[4];
    const float* Wq      = (const float*)d_in[5];
    const float* bq      = (const float*)d_in[6];
    const float* Wk      = (const float*)d_in[7];
    const float* bk      = (const float*)d_in[8];
    const float* Wv      = (const float*)d_in[9];
    const float* bv      = (const float*)d_in[10];
    const float* Wo      = (const float*)d_in[11];
    const float* bo      = (const float*)d_in[12];
    const float* ln1_w   = (const float*)d_in[13];
    const float* ln1_b   = (const float*)d_in[14];
    const float* ln2_w   = (const float*)d_in[15];
    const float* ln2_b   = (const float*)d_in[16];
    const float* gate_W  = (const float*)d_in[17];
    const float* eW1     = (const float*)d_in[18];
    const float* eb1     = (const float*)d_in[19];
    const float* eW2     = (const float*)d_in[20];
    const float* eb2     = (const float*)d_in[21];
    const float* enc_w   = (const float*)d_in[22];
    const float* enc_b   = (const float*)d_in[23];
    const float* hgW     = (const float*)d_in[24];
    const float* hW      = (const float*)d_in[25];
    const float* hb      = (const float*)d_in[26];
    float* out = (float*)d_out;

    const size_t TOKD = (size_t)NTOK * DM;   // 4194304
    float* ws   = (float*)d_ws;
    float* mean = ws;                // 8192
    float* stdd = ws + 8192;         // 8192
    float* B0   = ws + 16384;        // xn -> ktg
    float* B1   = B0 + TOKD;         // h
    float* B2   = B1 + TOKD;         // qb -> proj
    float* B3   = B2 + TOKD;         // kb -> vtg
    float* B4   = B3 + TOKD;         // vb -> attn out

    float* h = B1;

    dim3 blk(256);
    dim3 ggemm(DM/64, NTOK/64);      // (8, 128)

    revin_stats_kernel<<<dim3(BATCH*16), blk, 0, stream>>>(x, mean, stdd);
    revin_norm_kernel<<<dim3(NVAR/32, SEQ/32, BATCH), blk, 0, stream>>>(
        x, mean, stdd, revin_w, revin_b, B0);
    gemm_bias_kernel<<<ggemm, blk, 0, stream>>>(B0, emb_W, emb_b, h, NTOK, SEQ, DM);

    for (int l = 0; l < NL; ++l) {
        const float* wq = Wq + (size_t)l*DM*DM;
        const float* wk = Wk + (size_t)l*DM*DM;
        const float* wv = Wv + (size_t)l*DM*DM;
        const float* wo = Wo + (size_t)l*DM*DM;
        gemm_bias_kernel<<<ggemm, blk, 0, stream>>>(h, wq, bq + l*DM, B2, NTOK, DM, DM);
        gemm_bias_kernel<<<ggemm, blk, 0, stream>>>(h, wk, bk + l*DM, B3, NTOK, DM, DM);
        gemm_bias_kernel<<<ggemm, blk, 0, stream>>>(h, wv, bv + l*DM, B4, NTOK, DM, DM);
        // K: B3 -> B0 (ktg); then V: B4 -> B3 (vtg).  Sequential: 2nd reads B4,
        // writes B3 only after 1st (reading B3) completes (stream order).
        transpose_kv_kernel<<<dim3(64*16), blk, 0, stream>>>(B3, B0);
        transpose_kv_kernel<<<dim3(64*16), blk, 0, stream>>>(B4, B3);
        attn_kernel<<<dim3(BATCH*NH*(NVAR/8)), blk, 0, stream>>>(B2, B0, B3, B4);
        gemm_bias_kernel<<<ggemm, blk, 0, stream>>>(B4, wo, bo + l*DM, B2, NTOK, DM, DM);
        ln_kernel<<<dim3(NTOK), blk, 0, stream>>>(h, B2, ln1_w + l*DM, ln1_b + l*DM);
        moe_kernel<<<dim3(NTOK), blk, 0, stream>>>(
            h, B2, gate_W + (size_t)l*DM*NE,
            eW1 + (size_t)l*NE*DM*NF, eb1 + (size_t)l*NE*NF,
            eW2 + (size_t)l*NE*NF*DM, eb2 + (size_t)l*NE*DM);
        ln_kernel<<<dim3(NTOK), blk, 0, stream>>>(h, B2, ln2_w + l*DM, ln2_b + l*DM);
    }

    ln_kernel<<<dim3(NTOK), blk, 0, stream>>>(h, nullptr, enc_w, enc_b);
    head_kernel<<<dim3(NTOK), blk, 0, stream>>>(
        h, hgW, hW, hb, revin_w, revin_b, mean, stdd, out);
}

// Round 3
// 2207.286 us; speedup vs baseline: 3.2178x; 1.2217x over previous
//
#include <hip/hip_runtime.h>
#include <math.h>

#define BATCH 8
#define SEQ 512
#define NVAR 1024
#define DM 512
#define NH 8
#define DH 64
#define NE 8
#define NF 8
#define NL 2
#define NTOK (BATCH*NVAR)   // 8192
#define LN_EPS 1e-5f

// ---------------------------------------------------------------- RevIN stats
__global__ __launch_bounds__(256) void revin_stats_kernel(
        const float* __restrict__ x, float* __restrict__ mean, float* __restrict__ stdd) {
    int blk = blockIdx.x;            // b*16 + ntile
    int b = blk >> 4;
    int n0 = (blk & 15) << 6;
    int t = threadIdx.x;
    int ni = t & 63, sg = t >> 6;
    float s = 0.f, ss = 0.f;
    for (int sidx = sg; sidx < SEQ; sidx += 4) {
        float v = x[((size_t)b*SEQ + sidx)*NVAR + n0 + ni];
        s += v; ss += v*v;
    }
    __shared__ float rs[4][64], rq[4][64];
    rs[sg][ni] = s; rq[sg][ni] = ss;
    __syncthreads();
    if (t < 64) {
        float su = rs[0][t] + rs[1][t] + rs[2][t] + rs[3][t];
        float sq = rq[0][t] + rq[1][t] + rq[2][t] + rq[3][t];
        float m  = su / (float)SEQ;
        float var = sq / (float)SEQ - m*m;
        int n = n0 + t;
        mean[b*NVAR + n] = m;
        stdd[b*NVAR + n] = sqrtf(var + LN_EPS);
    }
}

// ------------------------------------------------- RevIN normalize + transpose
__global__ __launch_bounds__(256) void revin_norm_kernel(
        const float* __restrict__ x, const float* __restrict__ mean, const float* __restrict__ stdd,
        const float* __restrict__ rw, const float* __restrict__ rb, float* __restrict__ xn) {
    __shared__ float tile[32][33];
    int n0 = blockIdx.x << 5, s0 = blockIdx.y << 5, b = blockIdx.z;
    int t = threadIdx.x;
    int j = t & 31, i0 = t >> 5;
    for (int ii = i0; ii < 32; ii += 8)
        tile[ii][j] = x[((size_t)b*SEQ + s0 + ii)*NVAR + n0 + j];
    __syncthreads();
    int si = t & 31, j0 = t >> 5;
    for (int nj = j0; nj < 32; nj += 8) {
        int n = n0 + nj;
        float m = mean[b*NVAR + n], sd = stdd[b*NVAR + n];
        xn[((size_t)b*NVAR + n)*SEQ + s0 + si] = (tile[si][nj] - m) / sd * rw[n] + rb[n];
    }
}

// ---------------------------------------------------------------- fp32 GEMM
__global__ __launch_bounds__(256) void gemm_bias_kernel(
        const float* __restrict__ A, const float* __restrict__ W,
        const float* __restrict__ bias, float* __restrict__ C, int M, int K, int N) {
    __shared__ float As[16][65];
    __shared__ float Bs[16][64];
    int bm = blockIdx.y << 6, bn = blockIdx.x << 6;
    int t = threadIdx.x;
    int tx = t & 15, ty = t >> 4;
    int arow = t >> 4, acol = t & 15;
    int bcol = t & 63, brow = t >> 6;
    float acc[4][4] = {};
    for (int k0 = 0; k0 < K; k0 += 16) {
#pragma unroll
        for (int r = 0; r < 4; ++r)
            As[acol][arow + 16*r] = A[(size_t)(bm + arow + 16*r)*K + k0 + acol];
#pragma unroll
        for (int r = 0; r < 4; ++r)
            Bs[brow + 4*r][bcol] = W[(size_t)(k0 + brow + 4*r)*N + bn + bcol];
        __syncthreads();
#pragma unroll
        for (int kk = 0; kk < 16; ++kk) {
            float a0 = As[kk][ty*4+0], a1 = As[kk][ty*4+1];
            float a2 = As[kk][ty*4+2], a3 = As[kk][ty*4+3];
            float b0 = Bs[kk][tx*4+0], b1 = Bs[kk][tx*4+1];
            float b2 = Bs[kk][tx*4+2], b3 = Bs[kk][tx*4+3];
            acc[0][0] += a0*b0; acc[0][1] += a0*b1; acc[0][2] += a0*b2; acc[0][3] += a0*b3;
            acc[1][0] += a1*b0; acc[1][1] += a1*b1; acc[1][2] += a1*b2; acc[1][3] += a1*b3;
            acc[2][0] += a2*b0; acc[2][1] += a2*b1; acc[2][2] += a2*b2; acc[2][3] += a2*b3;
            acc[3][0] += a3*b0; acc[3][1] += a3*b1; acc[3][2] += a3*b2; acc[3][3] += a3*b3;
        }
        __syncthreads();
    }
#pragma unroll
    for (int i = 0; i < 4; ++i) {
        size_t row = bm + ty*4 + i;
#pragma unroll
        for (int jj = 0; jj < 4; ++jj) {
            int col = bn + tx*4 + jj;
            C[row*N + col] = acc[i][jj] + bias[col];
        }
    }
}

// --------------------------------------------- K/V head-transpose (per layer)
__global__ __launch_bounds__(256) void transpose_kv_kernel(
        const float* __restrict__ in, float* __restrict__ outp) {
    __shared__ float tile[64][65];
    int blk = blockIdx.x;            // bh(64) * ntile(16)
    int bh = blk >> 4, n0 = (blk & 15) << 6;
    int b = bh >> 3, h = bh & 7;
    int t = threadIdx.x;
    int j = t & 63, i0 = t >> 6;
    for (int i = i0; i < 64; i += 4)
        tile[i][j] = in[((size_t)b*NVAR + n0 + i)*DM + h*DH + j];
    __syncthreads();
    int n = t & 63, c0 = t >> 6;
    for (int c = c0; c < 64; c += 4)
        outp[((size_t)bh*DH + c)*NVAR + n0 + n] = tile[n][c];
}

// ---------------------------------------------------------------- attention
__global__ __launch_bounds__(256) void attn_kernel(
        const float* __restrict__ q, const float* __restrict__ kt,
        const float* __restrict__ vt, float* __restrict__ o) {
    __shared__ float qs[8][64];
    __shared__ float pl[8][1024];
    __shared__ float red[8][32];
    __shared__ float denom[8];
    int blk = blockIdx.x;
    int qb = blk & 127, bh = blk >> 7;
    int b = bh >> 3, hh = bh & 7;
    int q0 = qb << 3;
    int t = threadIdx.x;
    size_t bbase = (size_t)b * NVAR;
    size_t kvbase = (size_t)bh * DH * NVAR;

    for (int idx = t; idx < 512; idx += 256) {
        int r = idx >> 6, j = idx & 63;
        qs[r][j] = q[(bbase + q0 + r)*DM + hh*DH + j];
    }
    __syncthreads();

    // phase 1: S = Q K^T
    {
        int m0 = t << 2;
        float acc[8][4] = {};
#pragma unroll 4
        for (int c0 = 0; c0 < 64; c0 += 4) {
            float4 kv0 = *(const float4*)&kt[kvbase + (size_t)(c0+0)*NVAR + m0];
            float4 kv1 = *(const float4*)&kt[kvbase + (size_t)(c0+1)*NVAR + m0];
            float4 kv2 = *(const float4*)&kt[kvbase + (size_t)(c0+2)*NVAR + m0];
            float4 kv3 = *(const float4*)&kt[kvbase + (size_t)(c0+3)*NVAR + m0];
#pragma unroll
            for (int r = 0; r < 8; ++r) {
                float4 qv = *(const float4*)&qs[r][c0];
                acc[r][0] += qv.x*kv0.x + qv.y*kv1.x + qv.z*kv2.x + qv.w*kv3.x;
                acc[r][1] += qv.x*kv0.y + qv.y*kv1.y + qv.z*kv2.y + qv.w*kv3.y;
                acc[r][2] += qv.x*kv0.z + qv.y*kv1.z + qv.z*kv2.z + qv.w*kv3.z;
                acc[r][3] += qv.x*kv0.w + qv.y*kv1.w + qv.z*kv2.w + qv.w*kv3.w;
            }
        }
#pragma unroll
        for (int r = 0; r < 8; ++r) {
            float4 sv;
            sv.x = acc[r][0]*0.125f; sv.y = acc[r][1]*0.125f;
            sv.z = acc[r][2]*0.125f; sv.w = acc[r][3]*0.125f;
            *(float4*)&pl[r][m0] = sv;
        }
    }
    __syncthreads();

    // phase 2: softmax per row
    {
        int row = t >> 5, l32 = t & 31;
        float mx = -1e30f;
        for (int m = l32; m < 1024; m += 32) mx = fmaxf(mx, pl[row][m]);
        red[row][l32] = mx;
        __syncthreads();
        float rmax = red[row][0];
#pragma unroll
        for (int i = 1; i < 32; ++i) rmax = fmaxf(rmax, red[row][i]);
        __syncthreads();
        float sm = 0.f;
        for (int m = l32; m < 1024; m += 32) {
            float ev = __expf(pl[row][m] - rmax);
            pl[row][m] = ev; sm += ev;
        }
        red[row][l32] = sm;
        __syncthreads();
        if (l32 == 0) {
            float dsum = 0.f;
            for (int i = 0; i < 32; ++i) dsum += red[row][i];
            denom[row] = dsum;
        }
        __syncthreads();
    }

    // phase 3: O = P V
    {
        int mg = t & 3, jslot = (t >> 2) & 7, mhalf = (t >> 5) & 1, wv = t >> 6;
        int j0 = wv*16 + jslot, j1 = j0 + 8;
        const float* vtp0 = vt + kvbase + (size_t)j0*NVAR;
        const float* vtp1 = vt + kvbase + (size_t)j1*NVAR;
        float a0[8] = {}, a1[8] = {};
#pragma unroll 2
        for (int ch = 0; ch < 32; ++ch) {
            int m0 = mhalf*512 + ch*16 + mg*4;
            float4 vv0 = *(const float4*)&vtp0[m0];
            float4 vv1 = *(const float4*)&vtp1[m0];
#pragma unroll
            for (int r = 0; r < 8; ++r) {
                float4 pv = *(const float4*)&pl[r][m0];
                a0[r] += pv.x*vv0.x + pv.y*vv0.y + pv.z*vv0.z + pv.w*vv0.w;
                a1[r] += pv.x*vv1.x + pv.y*vv1.y + pv.z*vv1.z + pv.w*vv1.w;
            }
        }
#pragma unroll
        for (int r = 0; r < 8; ++r) {
            a0[r] += __shfl_xor(a0[r], 1);  a1[r] += __shfl_xor(a1[r], 1);
            a0[r] += __shfl_xor(a0[r], 2);  a1[r] += __shfl_xor(a1[r], 2);
            a0[r] += __shfl_xor(a0[r], 32); a1[r] += __shfl_xor(a1[r], 32);
        }
        if (mg == 0 && mhalf == 0) {
#pragma unroll
            for (int r = 0; r < 8; ++r) {
                float inv = 1.0f / denom[r];
                size_t rowbase = (bbase + q0 + r)*DM + hh*DH;
                o[rowbase + j0] = a0[r] * inv;
                o[rowbase + j1] = a1[r] * inv;
            }
        }
    }
}

// ---------------------------------------------------------------- LayerNorm
__global__ __launch_bounds__(256) void ln_kernel(
        float* __restrict__ h, const float* __restrict__ res,
        const float* __restrict__ w, const float* __restrict__ b) {
    int rowi = blockIdx.x, t = threadIdx.x;
    size_t base = (size_t)rowi * DM;
    float v0 = h[base + t], v1 = h[base + t + 256];
    if (res) { v0 += res[base + t]; v1 += res[base + t + 256]; }
    __shared__ float rs[256], rq[256];
    rs[t] = v0 + v1; rq[t] = v0*v0 + v1*v1;
    __syncthreads();
    for (int off = 128; off > 0; off >>= 1) {
        if (t < off) { rs[t] += rs[t+off]; rq[t] += rq[t+off]; }
        __syncthreads();
    }
    float m = rs[0] / (float)DM;
    float var = rq[0] / (float)DM - m*m;
    float inv = 1.0f / sqrtf(var + LN_EPS);
    h[base + t]       = (v0 - m)*inv * w[t]       + b[t];
    h[base + t + 256] = (v1 - m)*inv * w[t + 256] + b[t + 256];
}

__device__ __forceinline__ float gelu_exact(float xv) {
    return 0.5f * xv * (1.0f + erff(xv * 0.70710678118654752f));
}

// ---------------------------------------------------------------- MoE FFN
__global__ __launch_bounds__(256) void moe_kernel(
        const float* __restrict__ h, float* __restrict__ out,
        const float* __restrict__ gW, const float* __restrict__ W1, const float* __restrict__ b1,
        const float* __restrict__ W2, const float* __restrict__ b2) {
    int tok = blockIdx.x, t = threadIdx.x;
    __shared__ float hs[DM];
    __shared__ float red[32][8];
    __shared__ float glog[8];
    __shared__ float hmid[8];
    __shared__ float wsel[2];
    __shared__ int   esel[2];
    size_t base = (size_t)tok * DM;
    hs[t] = h[base + t]; hs[t + 256] = h[base + t + 256];
    __syncthreads();
    int e = t & 7, i0 = t >> 3;
    {
        float a = 0.f;
        for (int i = i0; i < DM; i += 32) a += hs[i] * gW[i*NE + e];
        red[i0][e] = a;
    }
    __syncthreads();
    if (t < 8) { float sv = 0.f; for (int i = 0; i < 32; ++i) sv += red[i][t]; glog[t] = sv; }
    __syncthreads();
    if (t == 0) {
        float m0 = -1e30f, m1 = -1e30f; int s0i = 0, s1i = 0;
        for (int ei = 0; ei < 8; ++ei) {
            float vv = glog[ei];
            if (vv > m0) { m1 = m0; s1i = s0i; m0 = vv; s0i = ei; }
            else if (vv > m1) { m1 = vv; s1i = ei; }
        }
        float Z = 0.f;
        for (int ei = 0; ei < 8; ++ei) Z += expf(glog[ei] - m0);
        wsel[0] = 1.0f / Z;
        wsel[1] = expf(m1 - m0) / Z;
        esel[0] = s0i; esel[1] = s1i;
    }
    __syncthreads();
    float o0 = 0.f, o1 = 0.f;
    for (int ks = 0; ks < 2; ++ks) {
        int ee = esel[ks]; float wk = wsel[ks];
        int f = t & 7;
        float a = 0.f;
        for (int i = i0; i < DM; i += 32) a += hs[i] * W1[((size_t)ee*DM + i)*NF + f];
        red[i0][f] = a;
        __syncthreads();
        if (t < 8) {
            float sv = b1[ee*NF + t];
            for (int i = 0; i < 32; ++i) sv += red[i][t];
            hmid[t] = gelu_exact(sv);
        }
        __syncthreads();
        float s0v = b2[ee*DM + t], s1v = b2[ee*DM + t + 256];
#pragma unroll
        for (int i = 0; i < NF; ++i) {
            float hm = hmid[i];
            const float* wp = W2 + ((size_t)ee*NF + i)*DM;
            s0v += hm * wp[t]; s1v += hm * wp[t + 256];
        }
        o0 += wk * s0v; o1 += wk * s1v;
        __syncthreads();
    }
    out[base + t] = o0; out[base + t + 256] = o1;
}

// ------------------------------------------------------------- head: init
__global__ __launch_bounds__(64) void head_init_kernel(int* __restrict__ cnt) {
    if (threadIdx.x < NE) cnt[threadIdx.x] = 0;
}

// ------------------------------------------------------------- head: route
// One wave per token: gate logits -> top2 -> bucket insert; zero out-acc row.
__global__ __launch_bounds__(256) void head_route_kernel(
        const float* __restrict__ h, const float* __restrict__ gW,
        int* __restrict__ cnt, int* __restrict__ idxlist, float* __restrict__ wlist,
        float* __restrict__ outacc) {
    int t = threadIdx.x;
    int wv = t >> 6, lane = t & 63;
    int tok = blockIdx.x * 4 + wv;
    size_t base = (size_t)tok * DM;
    // gating: lane = ks(3b)<<3 | e(3b)
    int e = lane & 7, ks = lane >> 3;
    float a = 0.f;
    const float* hp = h + base + ks*64;
    const float* gp = gW + e;
#pragma unroll 16
    for (int i = 0; i < 64; ++i) a += hp[i] * gp[(ks*64 + i)*NE];
    a += __shfl_xor(a, 8);
    a += __shfl_xor(a, 16);
    a += __shfl_xor(a, 32);
    // lanes 0..7 now hold logit for expert lane
    float l0 = __shfl(a, 0), l1 = __shfl(a, 1), l2 = __shfl(a, 2), l3 = __shfl(a, 3);
    float l4 = __shfl(a, 4), l5 = __shfl(a, 5), l6 = __shfl(a, 6), l7 = __shfl(a, 7);
    if (lane == 0) {
        float lg[8] = {l0,l1,l2,l3,l4,l5,l6,l7};
        float m0 = -1e30f, m1 = -1e30f; int s0i = 0, s1i = 0;
        for (int ei = 0; ei < 8; ++ei) {
            float vv = lg[ei];
            if (vv > m0) { m1 = m0; s1i = s0i; m0 = vv; s0i = ei; }
            else if (vv > m1) { m1 = vv; s1i = ei; }
        }
        float Z = 0.f;
        for (int ei = 0; ei < 8; ++ei) Z += __expf(lg[ei] - m0);
        float w0 = 1.0f / Z;
        float w1 = __expf(m1 - m0) / Z;
        int p0 = atomicAdd(&cnt[s0i], 1);
        idxlist[s0i*NTOK + p0] = tok; wlist[s0i*NTOK + p0] = w0;
        int p1 = atomicAdd(&cnt[s1i], 1);
        idxlist[s1i*NTOK + p1] = tok; wlist[s1i*NTOK + p1] = w1;
    }
    // zero the accumulator row
#pragma unroll
    for (int j = 0; j < 8; ++j) outacc[base + j*64 + lane] = 0.f;
}

// ------------------------------------------------------------- head: grouped GEMM
// block: (coltile x, mtile y, expert z).  Gathers <=64 token rows, computes
// [64x512]@[512x64], scatter-adds w*(acc+bias) into outacc with fp32 atomics.
__global__ __launch_bounds__(256) void head_gemm_kernel(
        const float* __restrict__ h, const float* __restrict__ HW, const float* __restrict__ Hb,
        const int* __restrict__ cnt, const int* __restrict__ idxlist,
        const float* __restrict__ wlist, float* __restrict__ outacc) {
    int e = blockIdx.z;
    int cnt_e = cnt[e];
    int m0 = blockIdx.y << 6;
    if (m0 >= cnt_e) return;
    int rv = cnt_e - m0; if (rv > 64) rv = 64;
    int bn = blockIdx.x << 6;
    int t = threadIdx.x;

    __shared__ float As[16][65];
    __shared__ float Bs[16][64];
    __shared__ int   idxs[64];
    __shared__ float ws[64];
    if (t < 64) {
        if (t < rv) { idxs[t] = idxlist[e*NTOK + m0 + t]; ws[t] = wlist[e*NTOK + m0 + t]; }
        else        { idxs[t] = idxlist[e*NTOK + m0];     ws[t] = 0.f; }
    }
    __syncthreads();

    const float* W = HW + (size_t)e*DM*DM;
    int tx = t & 15, ty = t >> 4;
    int arow = t >> 4, acol = t & 15;
    int bcol = t & 63, brow = t >> 6;
    float acc[4][4] = {};
    for (int k0 = 0; k0 < DM; k0 += 16) {
#pragma unroll
        for (int r = 0; r < 4; ++r)
            As[acol][arow + 16*r] = h[(size_t)idxs[arow + 16*r]*DM + k0 + acol];
#pragma unroll
        for (int r = 0; r < 4; ++r)
            Bs[brow + 4*r][bcol] = W[(size_t)(k0 + brow + 4*r)*DM + bn + bcol];
        __syncthreads();
#pragma unroll
        for (int kk = 0; kk < 16; ++kk) {
            float a0 = As[kk][ty*4+0], a1 = As[kk][ty*4+1];
            float a2 = As[kk][ty*4+2], a3 = As[kk][ty*4+3];
            float b0 = Bs[kk][tx*4+0], b1 = Bs[kk][tx*4+1];
            float b2 = Bs[kk][tx*4+2], b3 = Bs[kk][tx*4+3];
            acc[0][0] += a0*b0; acc[0][1] += a0*b1; acc[0][2] += a0*b2; acc[0][3] += a0*b3;
            acc[1][0] += a1*b0; acc[1][1] += a1*b1; acc[1][2] += a1*b2; acc[1][3] += a1*b3;
            acc[2][0] += a2*b0; acc[2][1] += a2*b1; acc[2][2] += a2*b2; acc[2][3] += a2*b3;
            acc[3][0] += a3*b0; acc[3][1] += a3*b1; acc[3][2] += a3*b2; acc[3][3] += a3*b3;
        }
        __syncthreads();
    }
#pragma unroll
    for (int i = 0; i < 4; ++i) {
        int rloc = ty*4 + i;
        if (rloc < rv) {
            float wk = ws[rloc];
            size_t base = (size_t)idxs[rloc]*DM;
#pragma unroll
            for (int jj = 0; jj < 4; ++jj) {
                int col = bn + tx*4 + jj;
                atomicAdd(&outacc[base + col], wk*(acc[i][jj] + Hb[e*DM + col]));
            }
        }
    }
}

// ------------------------------------------------------------- head: denorm
__global__ __launch_bounds__(256) void head_denorm_kernel(
        const float* __restrict__ outacc,
        const float* __restrict__ rw, const float* __restrict__ rb,
        const float* __restrict__ mean, const float* __restrict__ stdd,
        float* __restrict__ out) {
    int tok = blockIdx.x, t = threadIdx.x;
    int n = tok & (NVAR - 1);
    size_t base = (size_t)tok * DM;
    float mn = mean[tok], sd = stdd[tok];
    float rwv = rw[n] + 1e-10f, rbv = rb[n];
    float o0 = outacc[base + t], o1 = outacc[base + t + 256];
    out[base + t]       = (o0 - rbv) / rwv * sd + mn;
    out[base + t + 256] = (o1 - rbv) / rwv * sd + mn;
}

// ---------------------------------------------------------------- launch
extern "C" void kernel_launch(void* const* d_in, const int* in_sizes, int n_in,
                              void* d_out, int out_size, void* d_ws, size_t ws_size,
                              hipStream_t stream) {
    const float* x       = (const float*)d_in[0];
    const float* revin_w = (const float*)d_in[1];
    const float* revin_b = (const float*)d_in[2];
    const float* emb_W   = (const float*)d_in[3];
    const float* emb_b   = (const float*)d_in[4];
    const float* Wq      = (const float*)d_in[5];
    const float* bq      = (const float*)d_in[6];
    const float* Wk      = (const float*)d_in[7];
    const float* bk      = (const float*)d_in[8];
    const float* Wv      = (const float*)d_in[9];
    const float* bv      = (const float*)d_in[10];
    const float* Wo      = (const float*)d_in[11];
    const float* bo      = (const float*)d_in[12];
    const float* ln1_w   = (const float*)d_in[13];
    const float* ln1_b   = (const float*)d_in[14];
    const float* ln2_w   = (const float*)d_in[15];
    const float* ln2_b   = (const float*)d_in[16];
    const float* gate_W  = (const float*)d_in[17];
    const float* eW1     = (const float*)d_in[18];
    const float* eb1     = (const float*)d_in[19];
    const float* eW2     = (const float*)d_in[20];
    const float* eb2     = (const float*)d_in[21];
    const float* enc_w   = (const float*)d_in[22];
    const float* enc_b   = (const float*)d_in[23];
    const float* hgW     = (const float*)d_in[24];
    const float* hW      = (const float*)d_in[25];
    const float* hb      = (const float*)d_in[26];
    float* out = (float*)d_out;

    const size_t TOKD = (size_t)NTOK * DM;   // 4194304
    float* ws   = (float*)d_ws;
    float* mean = ws;                // 8192
    float* stdd = ws + 8192;         // 8192
    float* B0   = ws + 16384;        // xn -> ktg
    float* B1   = B0 + TOKD;         // h
    float* B2   = B1 + TOKD;         // qb -> proj
    float* B3   = B2 + TOKD;         // kb -> vtg
    float* B4   = B3 + TOKD;         // vb -> attn out / head outacc
    float* tail = B4 + TOKD;
    int*   cnt     = (int*)tail;                 // 8
    int*   idxlist = (int*)(tail + 16);          // 8*8192
    float* wlist   = tail + 16 + NE*NTOK;        // 8*8192

    float* h = B1;

    dim3 blk(256);
    dim3 ggemm(DM/64, NTOK/64);      // (8, 128)

    revin_stats_kernel<<<dim3(BATCH*16), blk, 0, stream>>>(x, mean, stdd);
    revin_norm_kernel<<<dim3(NVAR/32, SEQ/32, BATCH), blk, 0, stream>>>(
        x, mean, stdd, revin_w, revin_b, B0);
    gemm_bias_kernel<<<ggemm, blk, 0, stream>>>(B0, emb_W, emb_b, h, NTOK, SEQ, DM);

    for (int l = 0; l < NL; ++l) {
        const float* wq = Wq + (size_t)l*DM*DM;
        const float* wk = Wk + (size_t)l*DM*DM;
        const float* wv = Wv + (size_t)l*DM*DM;
        const float* wo = Wo + (size_t)l*DM*DM;
        gemm_bias_kernel<<<ggemm, blk, 0, stream>>>(h, wq, bq + l*DM, B2, NTOK, DM, DM);
        gemm_bias_kernel<<<ggemm, blk, 0, stream>>>(h, wk, bk + l*DM, B3, NTOK, DM, DM);
        gemm_bias_kernel<<<ggemm, blk, 0, stream>>>(h, wv, bv + l*DM, B4, NTOK, DM, DM);
        transpose_kv_kernel<<<dim3(64*16), blk, 0, stream>>>(B3, B0);
        transpose_kv_kernel<<<dim3(64*16), blk, 0, stream>>>(B4, B3);
        attn_kernel<<<dim3(BATCH*NH*(NVAR/8)), blk, 0, stream>>>(B2, B0, B3, B4);
        gemm_bias_kernel<<<ggemm, blk, 0, stream>>>(B4, wo, bo + l*DM, B2, NTOK, DM, DM);
        ln_kernel<<<dim3(NTOK), blk, 0, stream>>>(h, B2, ln1_w + l*DM, ln1_b + l*DM);
        moe_kernel<<<dim3(NTOK), blk, 0, stream>>>(
            h, B2, gate_W + (size_t)l*DM*NE,
            eW1 + (size_t)l*NE*DM*NF, eb1 + (size_t)l*NE*NF,
            eW2 + (size_t)l*NE*NF*DM, eb2 + (size_t)l*NE*DM);
        ln_kernel<<<dim3(NTOK), blk, 0, stream>>>(h, B2, ln2_w + l*DM, ln2_b + l*DM);
    }

    ln_kernel<<<dim3(NTOK), blk, 0, stream>>>(h, nullptr, enc_w, enc_b);

    // MoE projection head: route -> grouped GEMM -> denorm
    head_init_kernel<<<dim3(1), dim3(64), 0, stream>>>(cnt);
    head_route_kernel<<<dim3(NTOK/4), blk, 0, stream>>>(h, hgW, cnt, idxlist, wlist, B4);
    head_gemm_kernel<<<dim3(DM/64, NTOK/64, NE), blk, 0, stream>>>(
        h, hW, hb, cnt, idxlist, wlist, B4);
    head_denorm_kernel<<<dim3(NTOK), blk, 0, stream>>>(
        B4, revin_w, revin_b, mean, stdd, out);
}

// Round 5
// 1260.969 us; speedup vs baseline: 5.6326x; 1.7505x over previous
//
#include <hip/hip_runtime.h>
#include <math.h>

#define BATCH 8
#define SEQ 512
#define NVAR 1024
#define DM 512
#define NH 8
#define DH 64
#define NE 8
#define NF 8
#define NL 2
#define NTOK (BATCH*NVAR)   // 8192
#define LN_EPS 1e-5f
#define LSC 2048.0f
#define ILSC (1.0f/2048.0f)

typedef __attribute__((ext_vector_type(8))) _Float16 f16x8;
typedef __attribute__((ext_vector_type(4))) float f32x4;
#define MFMA16 __builtin_amdgcn_mfma_f32_16x16x32_f16

__device__ __forceinline__ void fsplit(float v, _Float16& hi, _Float16& lo) {
    hi = (_Float16)v;
    lo = (_Float16)((v - (float)hi) * LSC);
}
__device__ __forceinline__ float frec(_Float16 hi, _Float16 lo) {
    return (float)hi + (float)lo * ILSC;
}

// ---------------------------------------------------------------- RevIN stats
__global__ __launch_bounds__(256) void revin_stats_kernel(
        const float* __restrict__ x, float* __restrict__ mean, float* __restrict__ stdd) {
    int blk = blockIdx.x;            // b*16 + ntile
    int b = blk >> 4;
    int n0 = (blk & 15) << 6;
    int t = threadIdx.x;
    int ni = t & 63, sg = t >> 6;
    float s = 0.f, ss = 0.f;
    for (int sidx = sg; sidx < SEQ; sidx += 4) {
        float v = x[((size_t)b*SEQ + sidx)*NVAR + n0 + ni];
        s += v; ss += v*v;
    }
    __shared__ float rs[4][64], rq[4][64];
    rs[sg][ni] = s; rq[sg][ni] = ss;
    __syncthreads();
    if (t < 64) {
        float su = rs[0][t] + rs[1][t] + rs[2][t] + rs[3][t];
        float sq = rq[0][t] + rq[1][t] + rq[2][t] + rq[3][t];
        float m  = su / (float)SEQ;
        float var = sq / (float)SEQ - m*m;
        int n = n0 + t;
        mean[b*NVAR + n] = m;
        stdd[b*NVAR + n] = sqrtf(var + LN_EPS);
    }
}

// ------------------------------- RevIN normalize + transpose (split f16 out)
__global__ __launch_bounds__(256) void revin_norm_kernel(
        const float* __restrict__ x, const float* __restrict__ mean, const float* __restrict__ stdd,
        const float* __restrict__ rw, const float* __restrict__ rb,
        _Float16* __restrict__ xnhi, _Float16* __restrict__ xnlo) {
    __shared__ float tile[32][33];
    int n0 = blockIdx.x << 5, s0 = blockIdx.y << 5, b = blockIdx.z;
    int t = threadIdx.x;
    int j = t & 31, i0 = t >> 5;
    for (int ii = i0; ii < 32; ii += 8)
        tile[ii][j] = x[((size_t)b*SEQ + s0 + ii)*NVAR + n0 + j];
    __syncthreads();
    int si = t & 31, j0 = t >> 5;
    for (int nj = j0; nj < 32; nj += 8) {
        int n = n0 + nj;
        float m = mean[b*NVAR + n], sd = stdd[b*NVAR + n];
        float v = (tile[si][nj] - m) / sd * rw[n] + rb[n];
        _Float16 h_, l_; fsplit(v, h_, l_);
        size_t idx = ((size_t)b*NVAR + n)*SEQ + s0 + si;
        xnhi[idx] = h_; xnlo[idx] = l_;
    }
}

// ----------------------- weight transpose+split: [K,N] -> [N,K] f16 hi/lo
struct WSrcs { const float* p[9]; };
__global__ __launch_bounds__(256) void transpose_w_kernel(
        WSrcs srcs, _Float16* __restrict__ whi, _Float16* __restrict__ wlo) {
    const float* W = srcs.p[blockIdx.z];
    _Float16* oh = whi + (size_t)blockIdx.z * DM * DM;
    _Float16* ol = wlo + (size_t)blockIdx.z * DM * DM;
    __shared__ float tile[64][65];
    int k0 = blockIdx.x << 6, n0 = blockIdx.y << 6;
    int t = threadIdx.x;
    for (int idx = t; idx < 4096; idx += 256) {
        int k = idx >> 6, n = idx & 63;
        tile[k][n] = W[(size_t)(k0 + k)*DM + n0 + n];
    }
    __syncthreads();
    for (int idx = t; idx < 4096; idx += 256) {
        int n = idx >> 6, k = idx & 63;
        _Float16 h_, l_; fsplit(tile[k][n], h_, l_);
        size_t o = (size_t)(n0 + n)*DM + k0 + k;
        oh[o] = h_; ol[o] = l_;
    }
}

// ------------------------------------------- fp16x2 MFMA GEMM (fp32-grade)
// C[M,N] = A[M,K] @ Wt[N,K]^T + bias, A/W given as hi/lo f16 planes.
// 128x64 tile, BK=32, 4 waves; wave owns 32 rows (2 x 16).
__global__ __launch_bounds__(256) void gemm_f16x2_kernel(
        const _Float16* __restrict__ Ahg, const _Float16* __restrict__ Alg,
        const _Float16* __restrict__ Whg, const _Float16* __restrict__ Wlg,
        const float* __restrict__ bias, float* __restrict__ C,
        _Float16* __restrict__ Chi, _Float16* __restrict__ Clo,
        int M, int K, int N) {
    __shared__ _Float16 sAh[128][40], sAl[128][40];
    __shared__ _Float16 sBh[64][40],  sBl[64][40];
    int bm = blockIdx.y << 7, bn = blockIdx.x << 6;
    int t = threadIdx.x;
    int w = t >> 6, lane = t & 63, m16 = lane & 15, quad = lane >> 4;
    int ra = t >> 1,  ca = (t & 1) << 4;   // A: 128 rows x 2 groups of 16
    int rb = t >> 2,  cb = (t & 3) << 3;   // B: 64 rows x 4 groups of 8
    f32x4 a1[2][4] = {}, a2[2][4] = {};
    for (int k0 = 0; k0 < K; k0 += 32) {
        size_t ga = (size_t)(bm + ra)*K + k0 + ca;
        size_t gb = (size_t)(bn + rb)*K + k0 + cb;
        *(uint4*)&sAh[ra][ca]   = *(const uint4*)&Ahg[ga];
        *(uint4*)&sAh[ra][ca+8] = *(const uint4*)&Ahg[ga + 8];
        *(uint4*)&sAl[ra][ca]   = *(const uint4*)&Alg[ga];
        *(uint4*)&sAl[ra][ca+8] = *(const uint4*)&Alg[ga + 8];
        *(uint4*)&sBh[rb][cb]   = *(const uint4*)&Whg[gb];
        *(uint4*)&sBl[rb][cb]   = *(const uint4*)&Wlg[gb];
        __syncthreads();
        f16x8 bh_[4], bl_[4];
#pragma unroll
        for (int nt = 0; nt < 4; ++nt) {
            bh_[nt] = *(const f16x8*)&sBh[nt*16 + m16][quad*8];
            bl_[nt] = *(const f16x8*)&sBl[nt*16 + m16][quad*8];
        }
#pragma unroll
        for (int h2 = 0; h2 < 2; ++h2) {
            f16x8 ah = *(const f16x8*)&sAh[w*32 + h2*16 + m16][quad*8];
            f16x8 al = *(const f16x8*)&sAl[w*32 + h2*16 + m16][quad*8];
#pragma unroll
            for (int nt = 0; nt < 4; ++nt) {
                a1[h2][nt] = MFMA16(ah, bh_[nt], a1[h2][nt], 0, 0, 0);
                a2[h2][nt] = MFMA16(ah, bl_[nt], a2[h2][nt], 0, 0, 0);
                a2[h2][nt] = MFMA16(al, bh_[nt], a2[h2][nt], 0, 0, 0);
            }
        }
        __syncthreads();
    }
#pragma unroll
    for (int h2 = 0; h2 < 2; ++h2)
#pragma unroll
        for (int nt = 0; nt < 4; ++nt) {
            int col = bn + nt*16 + m16;
            float bv = bias[col];
#pragma unroll
            for (int r = 0; r < 4; ++r) {
                size_t row = bm + w*32 + h2*16 + quad*4 + r;
                float v = a1[h2][nt][r] + a2[h2][nt][r]*ILSC + bv;
                if (C) C[row*N + col] = v;
                if (Chi) {
                    _Float16 h_, l_; fsplit(v, h_, l_);
                    Chi[row*N + col] = h_; Clo[row*N + col] = l_;
                }
            }
        }
}

// ------------------- fp16x2 GEMM, transposed split output (V projection)
// out: vthi/vtlo [b*8+h][dh(64)][tok(1024)]   M=NTOK, K=N=DM fixed.
__global__ __launch_bounds__(256) void gemm_f16x2_vt_kernel(
        const _Float16* __restrict__ Ahg, const _Float16* __restrict__ Alg,
        const _Float16* __restrict__ Whg, const _Float16* __restrict__ Wlg,
        const float* __restrict__ bias,
        _Float16* __restrict__ vthi, _Float16* __restrict__ vtlo) {
    __shared__ _Float16 sAh[128][40], sAl[128][40];
    __shared__ _Float16 sBh[64][40],  sBl[64][40];
    __shared__ float Ct[128][65];
    int bm = blockIdx.y << 7, bn = blockIdx.x << 6;
    int t = threadIdx.x;
    int w = t >> 6, lane = t & 63, m16 = lane & 15, quad = lane >> 4;
    int ra = t >> 1,  ca = (t & 1) << 4;
    int rb = t >> 2,  cb = (t & 3) << 3;
    f32x4 a1[2][4] = {}, a2[2][4] = {};
    for (int k0 = 0; k0 < DM; k0 += 32) {
        size_t ga = (size_t)(bm + ra)*DM + k0 + ca;
        size_t gb = (size_t)(bn + rb)*DM + k0 + cb;
        *(uint4*)&sAh[ra][ca]   = *(const uint4*)&Ahg[ga];
        *(uint4*)&sAh[ra][ca+8] = *(const uint4*)&Ahg[ga + 8];
        *(uint4*)&sAl[ra][ca]   = *(const uint4*)&Alg[ga];
        *(uint4*)&sAl[ra][ca+8] = *(const uint4*)&Alg[ga + 8];
        *(uint4*)&sBh[rb][cb]   = *(const uint4*)&Whg[gb];
        *(uint4*)&sBl[rb][cb]   = *(const uint4*)&Wlg[gb];
        __syncthreads();
        f16x8 bh_[4], bl_[4];
#pragma unroll
        for (int nt = 0; nt < 4; ++nt) {
            bh_[nt] = *(const f16x8*)&sBh[nt*16 + m16][quad*8];
            bl_[nt] = *(const f16x8*)&sBl[nt*16 + m16][quad*8];
        }
#pragma unroll
        for (int h2 = 0; h2 < 2; ++h2) {
            f16x8 ah = *(const f16x8*)&sAh[w*32 + h2*16 + m16][quad*8];
            f16x8 al = *(const f16x8*)&sAl[w*32 + h2*16 + m16][quad*8];
#pragma unroll
            for (int nt = 0; nt < 4; ++nt) {
                a1[h2][nt] = MFMA16(ah, bh_[nt], a1[h2][nt], 0, 0, 0);
                a2[h2][nt] = MFMA16(ah, bl_[nt], a2[h2][nt], 0, 0, 0);
                a2[h2][nt] = MFMA16(al, bh_[nt], a2[h2][nt], 0, 0, 0);
            }
        }
        __syncthreads();
    }
#pragma unroll
    for (int h2 = 0; h2 < 2; ++h2)
#pragma unroll
        for (int nt = 0; nt < 4; ++nt) {
            float bv = bias[bn + nt*16 + m16];
#pragma unroll
            for (int r = 0; r < 4; ++r)
                Ct[w*32 + h2*16 + quad*4 + r][nt*16 + m16] = a1[h2][nt][r] + a2[h2][nt][r]*ILSC + bv;
        }
    __syncthreads();
    int b = bm >> 10, tokn0 = bm & 1023, hh = bn >> 6;
    int dh = t >> 2, tg = (t & 3) << 4;
    size_t rowb = ((size_t)(b*8 + hh)*64 + dh)*NVAR + tokn0;
    for (int hb = 0; hb < 2; ++hb) {
        int tl0 = hb*64 + tg;
        unsigned short hbuf[16], lbuf[16];
#pragma unroll
        for (int i = 0; i < 16; ++i) {
            _Float16 h_, l_; fsplit(Ct[tl0 + i][dh], h_, l_);
            hbuf[i] = __builtin_bit_cast(unsigned short, h_);
            lbuf[i] = __builtin_bit_cast(unsigned short, l_);
        }
        uint4 uh0, uh1, ul0, ul1;
        uh0.x = hbuf[0]|(hbuf[1]<<16);  uh0.y = hbuf[2]|(hbuf[3]<<16);
        uh0.z = hbuf[4]|(hbuf[5]<<16);  uh0.w = hbuf[6]|(hbuf[7]<<16);
        uh1.x = hbuf[8]|(hbuf[9]<<16);  uh1.y = hbuf[10]|(hbuf[11]<<16);
        uh1.z = hbuf[12]|(hbuf[13]<<16);uh1.w = hbuf[14]|(hbuf[15]<<16);
        ul0.x = lbuf[0]|(lbuf[1]<<16);  ul0.y = lbuf[2]|(lbuf[3]<<16);
        ul0.z = lbuf[4]|(lbuf[5]<<16);  ul0.w = lbuf[6]|(lbuf[7]<<16);
        ul1.x = lbuf[8]|(lbuf[9]<<16);  ul1.y = lbuf[10]|(lbuf[11]<<16);
        ul1.z = lbuf[12]|(lbuf[13]<<16);ul1.w = lbuf[14]|(lbuf[15]<<16);
        *(uint4*)&vthi[rowb + tl0]     = uh0;
        *(uint4*)&vthi[rowb + tl0 + 8] = uh1;
        *(uint4*)&vtlo[rowb + tl0]     = ul0;
        *(uint4*)&vtlo[rowb + tl0 + 8] = ul1;
    }
}

// ------------------------------------- flash attention, fp16x2 MFMA
// q/k: [tok][DM] hi/lo planes; vt: [bh][64][1024] hi/lo; o: [tok][DM] hi/lo.
__global__ __launch_bounds__(256) void attn_f16x2_kernel(
        const _Float16* __restrict__ qh, const _Float16* __restrict__ ql,
        const _Float16* __restrict__ kh, const _Float16* __restrict__ kl,
        const _Float16* __restrict__ vth, const _Float16* __restrict__ vtl,
        _Float16* __restrict__ oh, _Float16* __restrict__ ol) {
    __shared__ _Float16 Qh[64][72], Ql[64][72];
    __shared__ _Float16 Kh[64][72], Kl[64][72];
    __shared__ _Float16 Vh[64][72], Vl[64][72];
    __shared__ _Float16 Ph[64][72], Pl[64][72];
    int blk = blockIdx.x;
    int qt = blk & 15, bh = blk >> 4;
    int b = bh >> 3, hh = bh & 7;
    int q0 = qt << 6;
    int t = threadIdx.x;
    int w = t >> 6, lane = t & 63;
    int m16 = lane & 15, quad = lane >> 4;
    size_t bbase = (size_t)b * NVAR;
    size_t vbase = (size_t)bh * DH * NVAR;

    for (int idx = t; idx < 512; idx += 256) {
        int r = idx >> 3, cg = (idx & 7) << 3;
        size_t g = (bbase + q0 + r)*DM + hh*DH + cg;
        *(uint4*)&Qh[r][cg] = *(const uint4*)&qh[g];
        *(uint4*)&Ql[r][cg] = *(const uint4*)&ql[g];
    }
    float mrow[4] = {-1e30f,-1e30f,-1e30f,-1e30f};
    float lrow[4] = {0.f,0.f,0.f,0.f};
    f32x4 o1[4] = {}, o2[4] = {};

    for (int n0 = 0; n0 < NVAR; n0 += 64) {
        for (int idx = t; idx < 512; idx += 256) {
            int r = idx >> 3, cg = (idx & 7) << 3;
            size_t gk = (bbase + n0 + r)*DM + hh*DH + cg;
            size_t gv = vbase + (size_t)r*NVAR + n0 + cg;
            *(uint4*)&Kh[r][cg] = *(const uint4*)&kh[gk];
            *(uint4*)&Kl[r][cg] = *(const uint4*)&kl[gk];
            *(uint4*)&Vh[r][cg] = *(const uint4*)&vth[gv];
            *(uint4*)&Vl[r][cg] = *(const uint4*)&vtl[gv];
        }
        __syncthreads();

        f32x4 s1[4] = {}, s2[4] = {};
#pragma unroll
        for (int ks = 0; ks < 2; ++ks) {
            f16x8 ah = *(const f16x8*)&Qh[w*16 + m16][ks*32 + quad*8];
            f16x8 al = *(const f16x8*)&Ql[w*16 + m16][ks*32 + quad*8];
#pragma unroll
            for (int nt = 0; nt < 4; ++nt) {
                f16x8 bh_ = *(const f16x8*)&Kh[nt*16 + m16][ks*32 + quad*8];
                f16x8 bl_ = *(const f16x8*)&Kl[nt*16 + m16][ks*32 + quad*8];
                s1[nt] = MFMA16(ah, bh_, s1[nt], 0, 0, 0);
                s2[nt] = MFMA16(ah, bl_, s2[nt], 0, 0, 0);
                s2[nt] = MFMA16(al, bh_, s2[nt], 0, 0, 0);
            }
        }

        float pbuf[4][4];
#pragma unroll
        for (int r = 0; r < 4; ++r) {
            float sv0 = (s1[0][r] + s2[0][r]*ILSC)*0.125f;
            float sv1 = (s1[1][r] + s2[1][r]*ILSC)*0.125f;
            float sv2 = (s1[2][r] + s2[2][r]*ILSC)*0.125f;
            float sv3 = (s1[3][r] + s2[3][r]*ILSC)*0.125f;
            float mx = fmaxf(fmaxf(sv0, sv1), fmaxf(sv2, sv3));
            mx = fmaxf(mx, __shfl_xor(mx, 1));
            mx = fmaxf(mx, __shfl_xor(mx, 2));
            mx = fmaxf(mx, __shfl_xor(mx, 4));
            mx = fmaxf(mx, __shfl_xor(mx, 8));
            float mnew = fmaxf(mrow[r], mx);
            float alpha = __expf(mrow[r] - mnew);
            float p0 = __expf(sv0 - mnew), p1 = __expf(sv1 - mnew);
            float p2 = __expf(sv2 - mnew), p3 = __expf(sv3 - mnew);
            float rs = p0 + p1 + p2 + p3;
            rs += __shfl_xor(rs, 1);
            rs += __shfl_xor(rs, 2);
            rs += __shfl_xor(rs, 4);
            rs += __shfl_xor(rs, 8);
            lrow[r] = lrow[r]*alpha + rs;
            mrow[r] = mnew;
            pbuf[0][r] = p0; pbuf[1][r] = p1; pbuf[2][r] = p2; pbuf[3][r] = p3;
#pragma unroll
            for (int nt = 0; nt < 4; ++nt) { o1[nt][r] *= alpha; o2[nt][r] *= alpha; }
        }
#pragma unroll
        for (int nt = 0; nt < 4; ++nt)
#pragma unroll
            for (int r = 0; r < 4; ++r) {
                _Float16 h_, l_; fsplit(pbuf[nt][r], h_, l_);
                Ph[w*16 + quad*4 + r][nt*16 + m16] = h_;
                Pl[w*16 + quad*4 + r][nt*16 + m16] = l_;
            }
        __syncthreads();

#pragma unroll
        for (int ks = 0; ks < 2; ++ks) {
            f16x8 ph = *(const f16x8*)&Ph[w*16 + m16][ks*32 + quad*8];
            f16x8 pl = *(const f16x8*)&Pl[w*16 + m16][ks*32 + quad*8];
#pragma unroll
            for (int nt = 0; nt < 4; ++nt) {
                f16x8 vh_ = *(const f16x8*)&Vh[nt*16 + m16][ks*32 + quad*8];
                f16x8 vl_ = *(const f16x8*)&Vl[nt*16 + m16][ks*32 + quad*8];
                o1[nt] = MFMA16(ph, vh_, o1[nt], 0, 0, 0);
                o2[nt] = MFMA16(ph, vl_, o2[nt], 0, 0, 0);
                o2[nt] = MFMA16(pl, vh_, o2[nt], 0, 0, 0);
            }
        }
        __syncthreads();
    }
#pragma unroll
    for (int r = 0; r < 4; ++r) {
        float inv = 1.0f / lrow[r];
        size_t rowp = (bbase + q0 + w*16 + quad*4 + r)*DM + hh*DH;
#pragma unroll
        for (int nt = 0; nt < 4; ++nt) {
            float ov = (o1[nt][r] + o2[nt][r]*ILSC) * inv;
            _Float16 h_, l_; fsplit(ov, h_, l_);
            oh[rowp + nt*16 + m16] = h_;
            ol[rowp + nt*16 + m16] = l_;
        }
    }
}

// ---------------------------------------------------------------- LayerNorm
__global__ __launch_bounds__(256) void ln_kernel(
        _Float16* __restrict__ hhi, _Float16* __restrict__ hlo,
        const float* __restrict__ res,
        const float* __restrict__ w, const float* __restrict__ b) {
    int rowi = blockIdx.x, t = threadIdx.x;
    size_t base = (size_t)rowi * DM;
    float v0 = frec(hhi[base + t], hlo[base + t]);
    float v1 = frec(hhi[base + t + 256], hlo[base + t + 256]);
    if (res) { v0 += res[base + t]; v1 += res[base + t + 256]; }
    __shared__ float rs[256], rq[256];
    rs[t] = v0 + v1; rq[t] = v0*v0 + v1*v1;
    __syncthreads();
    for (int off = 128; off > 0; off >>= 1) {
        if (t < off) { rs[t] += rs[t+off]; rq[t] += rq[t+off]; }
        __syncthreads();
    }
    float m = rs[0] / (float)DM;
    float var = rq[0] / (float)DM - m*m;
    float inv = 1.0f / sqrtf(var + LN_EPS);
    float y0 = (v0 - m)*inv * w[t]       + b[t];
    float y1 = (v1 - m)*inv * w[t + 256] + b[t + 256];
    _Float16 h0, l0, h1, l1;
    fsplit(y0, h0, l0); fsplit(y1, h1, l1);
    hhi[base + t] = h0;       hlo[base + t] = l0;
    hhi[base + t + 256] = h1; hlo[base + t + 256] = l1;
}

__device__ __forceinline__ float gelu_exact(float xv) {
    return 0.5f * xv * (1.0f + erff(xv * 0.70710678118654752f));
}

// ---------------------------------------------------------------- MoE FFN
__global__ __launch_bounds__(256) void moe_kernel(
        const _Float16* __restrict__ hhi, const _Float16* __restrict__ hlo,
        float* __restrict__ out,
        const float* __restrict__ gW, const float* __restrict__ W1, const float* __restrict__ b1,
        const float* __restrict__ W2, const float* __restrict__ b2) {
    int tok = blockIdx.x, t = threadIdx.x;
    __shared__ float hs[DM];
    __shared__ float red[32][8];
    __shared__ float glog[8];
    __shared__ float hmid[8];
    __shared__ float wsel[2];
    __shared__ int   esel[2];
    size_t base = (size_t)tok * DM;
    hs[t] = frec(hhi[base + t], hlo[base + t]);
    hs[t + 256] = frec(hhi[base + t + 256], hlo[base + t + 256]);
    __syncthreads();
    int e = t & 7, i0 = t >> 3;
    {
        float a = 0.f;
        for (int i = i0; i < DM; i += 32) a += hs[i] * gW[i*NE + e];
        red[i0][e] = a;
    }
    __syncthreads();
    if (t < 8) { float sv = 0.f; for (int i = 0; i < 32; ++i) sv += red[i][t]; glog[t] = sv; }
    __syncthreads();
    if (t == 0) {
        float m0 = -1e30f, m1 = -1e30f; int s0i = 0, s1i = 0;
        for (int ei = 0; ei < 8; ++ei) {
            float vv = glog[ei];
            if (vv > m0) { m1 = m0; s1i = s0i; m0 = vv; s0i = ei; }
            else if (vv > m1) { m1 = vv; s1i = ei; }
        }
        float Z = 0.f;
        for (int ei = 0; ei < 8; ++ei) Z += expf(glog[ei] - m0);
        wsel[0] = 1.0f / Z;
        wsel[1] = expf(m1 - m0) / Z;
        esel[0] = s0i; esel[1] = s1i;
    }
    __syncthreads();
    float o0 = 0.f, o1 = 0.f;
    for (int ks = 0; ks < 2; ++ks) {
        int ee = esel[ks]; float wk = wsel[ks];
        int f = t & 7;
        float a = 0.f;
        for (int i = i0; i < DM; i += 32) a += hs[i] * W1[((size_t)ee*DM + i)*NF + f];
        red[i0][f] = a;
        __syncthreads();
        if (t < 8) {
            float sv = b1[ee*NF + t];
            for (int i = 0; i < 32; ++i) sv += red[i][t];
            hmid[t] = gelu_exact(sv);
        }
        __syncthreads();
        float s0v = b2[ee*DM + t], s1v = b2[ee*DM + t + 256];
#pragma unroll
        for (int i = 0; i < NF; ++i) {
            float hm = hmid[i];
            const float* wp = W2 + ((size_t)ee*NF + i)*DM;
            s0v += hm * wp[t]; s1v += hm * wp[t + 256];
        }
        o0 += wk * s0v; o1 += wk * s1v;
        __syncthreads();
    }
    out[base + t] = o0; out[base + t + 256] = o1;
}

// ------------------------------------------------------------- head: init
__global__ __launch_bounds__(64) void head_init_kernel(int* __restrict__ cnt) {
    if (threadIdx.x < NE) cnt[threadIdx.x] = 0;
}

// ------------------------------------------------------------- head: route
__global__ __launch_bounds__(256) void head_route_kernel(
        const _Float16* __restrict__ hhi, const _Float16* __restrict__ hlo,
        const float* __restrict__ gW,
        int* __restrict__ cnt, int* __restrict__ idxlist, float* __restrict__ wlist,
        float* __restrict__ outacc) {
    int t = threadIdx.x;
    int wv = t >> 6, lane = t & 63;
    int tok = blockIdx.x * 4 + wv;
    size_t base = (size_t)tok * DM;
    int e = lane & 7, ks = lane >> 3;
    float a = 0.f;
    const _Float16* hph = hhi + base + ks*64;
    const _Float16* hpl = hlo + base + ks*64;
    const float* gp = gW + e;
#pragma unroll 16
    for (int i = 0; i < 64; ++i) a += frec(hph[i], hpl[i]) * gp[(ks*64 + i)*NE];
    a += __shfl_xor(a, 8);
    a += __shfl_xor(a, 16);
    a += __shfl_xor(a, 32);
    float l0 = __shfl(a, 0), l1 = __shfl(a, 1), l2 = __shfl(a, 2), l3 = __shfl(a, 3);
    float l4 = __shfl(a, 4), l5 = __shfl(a, 5), l6 = __shfl(a, 6), l7 = __shfl(a, 7);
    if (lane == 0) {
        float lg[8] = {l0,l1,l2,l3,l4,l5,l6,l7};
        float m0 = -1e30f, m1 = -1e30f; int s0i = 0, s1i = 0;
        for (int ei = 0; ei < 8; ++ei) {
            float vv = lg[ei];
            if (vv > m0) { m1 = m0; s1i = s0i; m0 = vv; s0i = ei; }
            else if (vv > m1) { m1 = vv; s1i = ei; }
        }
        float Z = 0.f;
        for (int ei = 0; ei < 8; ++ei) Z += __expf(lg[ei] - m0);
        float w0 = 1.0f / Z;
        float w1 = __expf(m1 - m0) / Z;
        int p0 = atomicAdd(&cnt[s0i], 1);
        idxlist[s0i*NTOK + p0] = tok; wlist[s0i*NTOK + p0] = w0;
        int p1 = atomicAdd(&cnt[s1i], 1);
        idxlist[s1i*NTOK + p1] = tok; wlist[s1i*NTOK + p1] = w1;
    }
#pragma unroll
    for (int j = 0; j < 8; ++j) outacc[base + j*64 + lane] = 0.f;
}

// ------------------------------------------------------------- head: grouped GEMM
__global__ __launch_bounds__(256) void head_gemm_kernel(
        const _Float16* __restrict__ hhi, const _Float16* __restrict__ hlo,
        const float* __restrict__ HW, const float* __restrict__ Hb,
        const int* __restrict__ cnt, const int* __restrict__ idxlist,
        const float* __restrict__ wlist, float* __restrict__ outacc) {
    int e = blockIdx.z;
    int cnt_e = cnt[e];
    int m0 = blockIdx.y << 6;
    if (m0 >= cnt_e) return;
    int rv = cnt_e - m0; if (rv > 64) rv = 64;
    int bn = blockIdx.x << 6;
    int t = threadIdx.x;

    __shared__ float As[16][65];
    __shared__ float Bs[16][64];
    __shared__ int   idxs[64];
    __shared__ float ws[64];
    if (t < 64) {
        if (t < rv) { idxs[t] = idxlist[e*NTOK + m0 + t]; ws[t] = wlist[e*NTOK + m0 + t]; }
        else        { idxs[t] = idxlist[e*NTOK + m0];     ws[t] = 0.f; }
    }
    __syncthreads();

    const float* W = HW + (size_t)e*DM*DM;
    int tx = t & 15, ty = t >> 4;
    int arow = t >> 4, acol = t & 15;
    int bcol = t & 63, brow = t >> 6;
    float acc[4][4] = {};
    for (int k0 = 0; k0 < DM; k0 += 16) {
#pragma unroll
        for (int r = 0; r < 4; ++r) {
            size_t g = (size_t)idxs[arow + 16*r]*DM + k0 + acol;
            As[acol][arow + 16*r] = frec(hhi[g], hlo[g]);
        }
#pragma unroll
        for (int r = 0; r < 4; ++r)
            Bs[brow + 4*r][bcol] = W[(size_t)(k0 + brow + 4*r)*DM + bn + bcol];
        __syncthreads();
#pragma unroll
        for (int kk = 0; kk < 16; ++kk) {
            float a0 = As[kk][ty*4+0], a1 = As[kk][ty*4+1];
            float a2 = As[kk][ty*4+2], a3 = As[kk][ty*4+3];
            float b0 = Bs[kk][tx*4+0], b1 = Bs[kk][tx*4+1];
            float b2 = Bs[kk][tx*4+2], b3 = Bs[kk][tx*4+3];
            acc[0][0] += a0*b0; acc[0][1] += a0*b1; acc[0][2] += a0*b2; acc[0][3] += a0*b3;
            acc[1][0] += a1*b0; acc[1][1] += a1*b1; acc[1][2] += a1*b2; acc[1][3] += a1*b3;
            acc[2][0] += a2*b0; acc[2][1] += a2*b1; acc[2][2] += a2*b2; acc[2][3] += a2*b3;
            acc[3][0] += a3*b0; acc[3][1] += a3*b1; acc[3][2] += a3*b2; acc[3][3] += a3*b3;
        }
        __syncthreads();
    }
#pragma unroll
    for (int i = 0; i < 4; ++i) {
        int rloc = ty*4 + i;
        if (rloc < rv) {
            float wk = ws[rloc];
            size_t base = (size_t)idxs[rloc]*DM;
#pragma unroll
            for (int jj = 0; jj < 4; ++jj) {
                int col = bn + tx*4 + jj;
                atomicAdd(&outacc[base + col], wk*(acc[i][jj] + Hb[e*DM + col]));
            }
        }
    }
}

// ------------------------------------------------------------- head: denorm
__global__ __launch_bounds__(256) void head_denorm_kernel(
        const float* __restrict__ outacc,
        const float* __restrict__ rw, const float* __restrict__ rb,
        const float* __restrict__ mean, const float* __restrict__ stdd,
        float* __restrict__ out) {
    int tok = blockIdx.x, t = threadIdx.x;
    int n = tok & (NVAR - 1);
    size_t base = (size_t)tok * DM;
    float mn = mean[tok], sd = stdd[tok];
    float rwv = rw[n] + 1e-10f, rbv = rb[n];
    float o0 = outacc[base + t], o1 = outacc[base + t + 256];
    out[base + t]       = (o0 - rbv) / rwv * sd + mn;
    out[base + t + 256] = (o1 - rbv) / rwv * sd + mn;
}

// ---------------------------------------------------------------- launch
extern "C" void kernel_launch(void* const* d_in, const int* in_sizes, int n_in,
                              void* d_out, int out_size, void* d_ws, size_t ws_size,
                              hipStream_t stream) {
    const float* x       = (const float*)d_in[0];
    const float* revin_w = (const float*)d_in[1];
    const float* revin_b = (const float*)d_in[2];
    const float* emb_W   = (const float*)d_in[3];
    const float* emb_b   = (const float*)d_in[4];
    const float* Wq      = (const float*)d_in[5];
    const float* bq      = (const float*)d_in[6];
    const float* Wk      = (const float*)d_in[7];
    const float* bk      = (const float*)d_in[8];
    const float* Wv      = (const float*)d_in[9];
    const float* bv      = (const float*)d_in[10];
    const float* Wo      = (const float*)d_in[11];
    const float* bo      = (const float*)d_in[12];
    const float* ln1_w   = (const float*)d_in[13];
    const float* ln1_b   = (const float*)d_in[14];
    const float* ln2_w   = (const float*)d_in[15];
    const float* ln2_b   = (const float*)d_in[16];
    const float* gate_W  = (const float*)d_in[17];
    const float* eW1     = (const float*)d_in[18];
    const float* eb1     = (const float*)d_in[19];
    const float* eW2     = (const float*)d_in[20];
    const float* eb2     = (const float*)d_in[21];
    const float* enc_w   = (const float*)d_in[22];
    const float* enc_b   = (const float*)d_in[23];
    const float* hgW     = (const float*)d_in[24];
    const float* hW      = (const float*)d_in[25];
    const float* hb      = (const float*)d_in[26];
    float* out = (float*)d_out;

    const size_t TOKD = (size_t)NTOK * DM;   // 4194304
    float* ws   = (float*)d_ws;
    float* mean = ws;
    float* stdd = ws + 8192;
    _Float16* hhi  = (_Float16*)(ws + 16384);
    _Float16* hlo  = hhi + TOKD;
    _Float16* qhi  = hlo + TOKD;     // also xn planes, attn O planes, head outacc (fp32 raw)
    _Float16* qlo  = qhi + TOKD;
    _Float16* khi  = qlo + TOKD;     // also proj fp32 raw
    _Float16* klo  = khi + TOKD;
    _Float16* vthi = klo + TOKD;
    _Float16* vtlo = vthi + TOKD;
    _Float16* whi  = vtlo + TOKD;    // 9 transposed split weights
    _Float16* wlo  = whi + (size_t)9*DM*DM;
    int*   cnt     = (int*)(wlo + (size_t)9*DM*DM);
    int*   idxlist = cnt + 16;
    float* wlist   = (float*)(idxlist + NE*NTOK);
    float* proj    = (float*)khi;
    float* outacc  = (float*)qhi;

    dim3 blk(256);
    dim3 ggemm(DM/64, NTOK/128);     // (8, 64)

    revin_stats_kernel<<<dim3(BATCH*16), blk, 0, stream>>>(x, mean, stdd);
    revin_norm_kernel<<<dim3(NVAR/32, SEQ/32, BATCH), blk, 0, stream>>>(
        x, mean, stdd, revin_w, revin_b, qhi, qlo);

    WSrcs srcs;
    srcs.p[0] = emb_W;
    for (int l = 0; l < NL; ++l) {
        srcs.p[1 + l*4 + 0] = Wq + (size_t)l*DM*DM;
        srcs.p[1 + l*4 + 1] = Wk + (size_t)l*DM*DM;
        srcs.p[1 + l*4 + 2] = Wv + (size_t)l*DM*DM;
        srcs.p[1 + l*4 + 3] = Wo + (size_t)l*DM*DM;
    }
    transpose_w_kernel<<<dim3(8, 8, 9), blk, 0, stream>>>(srcs, whi, wlo);

    gemm_f16x2_kernel<<<ggemm, blk, 0, stream>>>(
        qhi, qlo, whi, wlo, emb_b, nullptr, hhi, hlo, NTOK, SEQ, DM);

    for (int l = 0; l < NL; ++l) {
        size_t oq = (size_t)(1 + l*4 + 0)*DM*DM;
        size_t ok = (size_t)(1 + l*4 + 1)*DM*DM;
        size_t ov = (size_t)(1 + l*4 + 2)*DM*DM;
        size_t oo = (size_t)(1 + l*4 + 3)*DM*DM;
        gemm_f16x2_kernel<<<ggemm, blk, 0, stream>>>(
            hhi, hlo, whi + oq, wlo + oq, bq + l*DM, nullptr, qhi, qlo, NTOK, DM, DM);
        gemm_f16x2_kernel<<<ggemm, blk, 0, stream>>>(
            hhi, hlo, whi + ok, wlo + ok, bk + l*DM, nullptr, khi, klo, NTOK, DM, DM);
        gemm_f16x2_vt_kernel<<<ggemm, blk, 0, stream>>>(
            hhi, hlo, whi + ov, wlo + ov, bv + l*DM, vthi, vtlo);
        attn_f16x2_kernel<<<dim3(64*16), blk, 0, stream>>>(
            qhi, qlo, khi, klo, vthi, vtlo, qhi, qlo);
        gemm_f16x2_kernel<<<ggemm, blk, 0, stream>>>(
            qhi, qlo, whi + oo, wlo + oo, bo + l*DM, proj, nullptr, nullptr, NTOK, DM, DM);
        ln_kernel<<<dim3(NTOK), blk, 0, stream>>>(hhi, hlo, proj, ln1_w + l*DM, ln1_b + l*DM);
        moe_kernel<<<dim3(NTOK), blk, 0, stream>>>(
            hhi, hlo, proj, gate_W + (size_t)l*DM*NE,
            eW1 + (size_t)l*NE*DM*NF, eb1 + (size_t)l*NE*NF,
            eW2 + (size_t)l*NE*NF*DM, eb2 + (size_t)l*NE*DM);
        ln_kernel<<<dim3(NTOK), blk, 0, stream>>>(hhi, hlo, proj, ln2_w + l*DM, ln2_b + l*DM);
    }

    ln_kernel<<<dim3(NTOK), blk, 0, stream>>>(hhi, hlo, nullptr, enc_w, enc_b);

    head_init_kernel<<<dim3(1), dim3(64), 0, stream>>>(cnt);
    head_route_kernel<<<dim3(NTOK/4), blk, 0, stream>>>(
        hhi, hlo, hgW, cnt, idxlist, wlist, outacc);
    head_gemm_kernel<<<dim3(DM/64, NTOK/64, NE), blk, 0, stream>>>(
        hhi, hlo, hW, hb, cnt, idxlist, wlist, outacc);
    head_denorm_kernel<<<dim3(NTOK), blk, 0, stream>>>(
        outacc, revin_w, revin_b, mean, stdd, out);
}

// Round 6
// 1078.364 us; speedup vs baseline: 6.5864x; 1.1693x over previous
//
#include <hip/hip_runtime.h>
#include <math.h>

#define BATCH 8
#define SEQ 512
#define NVAR 1024
#define DM 512
#define NH 8
#define DH 64
#define NE 8
#define NF 8
#define NL 2
#define NTOK (BATCH*NVAR)   // 8192
#define LN_EPS 1e-5f
#define LSC 2048.0f
#define ILSC (1.0f/2048.0f)

typedef __attribute__((ext_vector_type(8))) _Float16 f16x8;
typedef __attribute__((ext_vector_type(4))) float f32x4;
#define MFMA16 __builtin_amdgcn_mfma_f32_16x16x32_f16

__device__ __forceinline__ void fsplit(float v, _Float16& hi, _Float16& lo) {
    hi = (_Float16)v;
    lo = (_Float16)((v - (float)hi) * LSC);
}
__device__ __forceinline__ float frec(_Float16 hi, _Float16 lo) {
    return (float)hi + (float)lo * ILSC;
}

// ---------------------------------------------------------------- RevIN stats
__global__ __launch_bounds__(256) void revin_stats_kernel(
        const float* __restrict__ x, float* __restrict__ mean, float* __restrict__ stdd) {
    int blk = blockIdx.x;            // b*16 + ntile
    int b = blk >> 4;
    int n0 = (blk & 15) << 6;
    int t = threadIdx.x;
    int ni = t & 63, sg = t >> 6;
    float s = 0.f, ss = 0.f;
    for (int sidx = sg; sidx < SEQ; sidx += 4) {
        float v = x[((size_t)b*SEQ + sidx)*NVAR + n0 + ni];
        s += v; ss += v*v;
    }
    __shared__ float rs[4][64], rq[4][64];
    rs[sg][ni] = s; rq[sg][ni] = ss;
    __syncthreads();
    if (t < 64) {
        float su = rs[0][t] + rs[1][t] + rs[2][t] + rs[3][t];
        float sq = rq[0][t] + rq[1][t] + rq[2][t] + rq[3][t];
        float m  = su / (float)SEQ;
        float var = sq / (float)SEQ - m*m;
        int n = n0 + t;
        mean[b*NVAR + n] = m;
        stdd[b*NVAR + n] = sqrtf(var + LN_EPS);
    }
}

// ------------------------------- RevIN normalize + transpose (split f16 out)
__global__ __launch_bounds__(256) void revin_norm_kernel(
        const float* __restrict__ x, const float* __restrict__ mean, const float* __restrict__ stdd,
        const float* __restrict__ rw, const float* __restrict__ rb,
        _Float16* __restrict__ xnhi, _Float16* __restrict__ xnlo) {
    __shared__ float tile[32][33];
    int n0 = blockIdx.x << 5, s0 = blockIdx.y << 5, b = blockIdx.z;
    int t = threadIdx.x;
    int j = t & 31, i0 = t >> 5;
    for (int ii = i0; ii < 32; ii += 8)
        tile[ii][j] = x[((size_t)b*SEQ + s0 + ii)*NVAR + n0 + j];
    __syncthreads();
    int si = t & 31, j0 = t >> 5;
    for (int nj = j0; nj < 32; nj += 8) {
        int n = n0 + nj;
        float m = mean[b*NVAR + n], sd = stdd[b*NVAR + n];
        float v = (tile[si][nj] - m) / sd * rw[n] + rb[n];
        _Float16 h_, l_; fsplit(v, h_, l_);
        size_t idx = ((size_t)b*NVAR + n)*SEQ + s0 + si;
        xnhi[idx] = h_; xnlo[idx] = l_;
    }
}

// ----------------------- weight transpose+split: [K,N] -> [N,K] f16 hi/lo
struct WSrcs { const float* p[9]; };
__global__ __launch_bounds__(256) void transpose_w_kernel(
        WSrcs srcs, _Float16* __restrict__ whi, _Float16* __restrict__ wlo) {
    const float* W = srcs.p[blockIdx.z];
    _Float16* oh = whi + (size_t)blockIdx.z * DM * DM;
    _Float16* ol = wlo + (size_t)blockIdx.z * DM * DM;
    __shared__ float tile[64][65];
    int k0 = blockIdx.x << 6, n0 = blockIdx.y << 6;
    int t = threadIdx.x;
    for (int idx = t; idx < 4096; idx += 256) {
        int k = idx >> 6, n = idx & 63;
        tile[k][n] = W[(size_t)(k0 + k)*DM + n0 + n];
    }
    __syncthreads();
    for (int idx = t; idx < 4096; idx += 256) {
        int n = idx >> 6, k = idx & 63;
        _Float16 h_, l_; fsplit(tile[k][n], h_, l_);
        size_t o = (size_t)(n0 + n)*DM + k0 + k;
        oh[o] = h_; ol[o] = l_;
    }
}

// ------------------------------------------- fp16x2 MFMA GEMM (fp32-grade)
// C[M,N] = A[M,K] @ Wt[N,K]^T + bias, A/W given as hi/lo f16 planes.
// 128x64 tile, BK=32, 4 waves; wave owns 32 rows (2 x 16).
__global__ __launch_bounds__(256) void gemm_f16x2_kernel(
        const _Float16* __restrict__ Ahg, const _Float16* __restrict__ Alg,
        const _Float16* __restrict__ Whg, const _Float16* __restrict__ Wlg,
        const float* __restrict__ bias, float* __restrict__ C,
        _Float16* __restrict__ Chi, _Float16* __restrict__ Clo,
        int M, int K, int N) {
    __shared__ _Float16 sAh[128][40], sAl[128][40];
    __shared__ _Float16 sBh[64][40],  sBl[64][40];
    int bm = blockIdx.y << 7, bn = blockIdx.x << 6;
    int t = threadIdx.x;
    int w = t >> 6, lane = t & 63, m16 = lane & 15, quad = lane >> 4;
    int ra = t >> 1,  ca = (t & 1) << 4;   // A: 128 rows x 2 groups of 16
    int rb = t >> 2,  cb = (t & 3) << 3;   // B: 64 rows x 4 groups of 8
    f32x4 a1[2][4] = {}, a2[2][4] = {};
    for (int k0 = 0; k0 < K; k0 += 32) {
        size_t ga = (size_t)(bm + ra)*K + k0 + ca;
        size_t gb = (size_t)(bn + rb)*K + k0 + cb;
        *(uint4*)&sAh[ra][ca]   = *(const uint4*)&Ahg[ga];
        *(uint4*)&sAh[ra][ca+8] = *(const uint4*)&Ahg[ga + 8];
        *(uint4*)&sAl[ra][ca]   = *(const uint4*)&Alg[ga];
        *(uint4*)&sAl[ra][ca+8] = *(const uint4*)&Alg[ga + 8];
        *(uint4*)&sBh[rb][cb]   = *(const uint4*)&Whg[gb];
        *(uint4*)&sBl[rb][cb]   = *(const uint4*)&Wlg[gb];
        __syncthreads();
        f16x8 bh_[4], bl_[4];
#pragma unroll
        for (int nt = 0; nt < 4; ++nt) {
            bh_[nt] = *(const f16x8*)&sBh[nt*16 + m16][quad*8];
            bl_[nt] = *(const f16x8*)&sBl[nt*16 + m16][quad*8];
        }
#pragma unroll
        for (int h2 = 0; h2 < 2; ++h2) {
            f16x8 ah = *(const f16x8*)&sAh[w*32 + h2*16 + m16][quad*8];
            f16x8 al = *(const f16x8*)&sAl[w*32 + h2*16 + m16][quad*8];
#pragma unroll
            for (int nt = 0; nt < 4; ++nt) {
                a1[h2][nt] = MFMA16(ah, bh_[nt], a1[h2][nt], 0, 0, 0);
                a2[h2][nt] = MFMA16(ah, bl_[nt], a2[h2][nt], 0, 0, 0);
                a2[h2][nt] = MFMA16(al, bh_[nt], a2[h2][nt], 0, 0, 0);
            }
        }
        __syncthreads();
    }
#pragma unroll
    for (int h2 = 0; h2 < 2; ++h2)
#pragma unroll
        for (int nt = 0; nt < 4; ++nt) {
            int col = bn + nt*16 + m16;
            float bv = bias[col];
#pragma unroll
            for (int r = 0; r < 4; ++r) {
                size_t row = bm + w*32 + h2*16 + quad*4 + r;
                float v = a1[h2][nt][r] + a2[h2][nt][r]*ILSC + bv;
                if (C) C[row*N + col] = v;
                if (Chi) {
                    _Float16 h_, l_; fsplit(v, h_, l_);
                    Chi[row*N + col] = h_; Clo[row*N + col] = l_;
                }
            }
        }
}

// ------------------- fp16x2 GEMM, transposed split output (V projection)
// out: vthi/vtlo [b*8+h][dh(64)][tok(1024)]   M=NTOK, K=N=DM fixed.
__global__ __launch_bounds__(256) void gemm_f16x2_vt_kernel(
        const _Float16* __restrict__ Ahg, const _Float16* __restrict__ Alg,
        const _Float16* __restrict__ Whg, const _Float16* __restrict__ Wlg,
        const float* __restrict__ bias,
        _Float16* __restrict__ vthi, _Float16* __restrict__ vtlo) {
    __shared__ _Float16 sAh[128][40], sAl[128][40];
    __shared__ _Float16 sBh[64][40],  sBl[64][40];
    __shared__ float Ct[128][65];
    int bm = blockIdx.y << 7, bn = blockIdx.x << 6;
    int t = threadIdx.x;
    int w = t >> 6, lane = t & 63, m16 = lane & 15, quad = lane >> 4;
    int ra = t >> 1,  ca = (t & 1) << 4;
    int rb = t >> 2,  cb = (t & 3) << 3;
    f32x4 a1[2][4] = {}, a2[2][4] = {};
    for (int k0 = 0; k0 < DM; k0 += 32) {
        size_t ga = (size_t)(bm + ra)*DM + k0 + ca;
        size_t gb = (size_t)(bn + rb)*DM + k0 + cb;
        *(uint4*)&sAh[ra][ca]   = *(const uint4*)&Ahg[ga];
        *(uint4*)&sAh[ra][ca+8] = *(const uint4*)&Ahg[ga + 8];
        *(uint4*)&sAl[ra][ca]   = *(const uint4*)&Alg[ga];
        *(uint4*)&sAl[ra][ca+8] = *(const uint4*)&Alg[ga + 8];
        *(uint4*)&sBh[rb][cb]   = *(const uint4*)&Whg[gb];
        *(uint4*)&sBl[rb][cb]   = *(const uint4*)&Wlg[gb];
        __syncthreads();
        f16x8 bh_[4], bl_[4];
#pragma unroll
        for (int nt = 0; nt < 4; ++nt) {
            bh_[nt] = *(const f16x8*)&sBh[nt*16 + m16][quad*8];
            bl_[nt] = *(const f16x8*)&sBl[nt*16 + m16][quad*8];
        }
#pragma unroll
        for (int h2 = 0; h2 < 2; ++h2) {
            f16x8 ah = *(const f16x8*)&sAh[w*32 + h2*16 + m16][quad*8];
            f16x8 al = *(const f16x8*)&sAl[w*32 + h2*16 + m16][quad*8];
#pragma unroll
            for (int nt = 0; nt < 4; ++nt) {
                a1[h2][nt] = MFMA16(ah, bh_[nt], a1[h2][nt], 0, 0, 0);
                a2[h2][nt] = MFMA16(ah, bl_[nt], a2[h2][nt], 0, 0, 0);
                a2[h2][nt] = MFMA16(al, bh_[nt], a2[h2][nt], 0, 0, 0);
            }
        }
        __syncthreads();
    }
#pragma unroll
    for (int h2 = 0; h2 < 2; ++h2)
#pragma unroll
        for (int nt = 0; nt < 4; ++nt) {
            float bv = bias[bn + nt*16 + m16];
#pragma unroll
            for (int r = 0; r < 4; ++r)
                Ct[w*32 + h2*16 + quad*4 + r][nt*16 + m16] = a1[h2][nt][r] + a2[h2][nt][r]*ILSC + bv;
        }
    __syncthreads();
    int b = bm >> 10, tokn0 = bm & 1023, hh = bn >> 6;
    int dh = t >> 2, tg = (t & 3) << 4;
    size_t rowb = ((size_t)(b*8 + hh)*64 + dh)*NVAR + tokn0;
    for (int hb = 0; hb < 2; ++hb) {
        int tl0 = hb*64 + tg;
        unsigned short hbuf[16], lbuf[16];
#pragma unroll
        for (int i = 0; i < 16; ++i) {
            _Float16 h_, l_; fsplit(Ct[tl0 + i][dh], h_, l_);
            hbuf[i] = __builtin_bit_cast(unsigned short, h_);
            lbuf[i] = __builtin_bit_cast(unsigned short, l_);
        }
        uint4 uh0, uh1, ul0, ul1;
        uh0.x = hbuf[0]|(hbuf[1]<<16);  uh0.y = hbuf[2]|(hbuf[3]<<16);
        uh0.z = hbuf[4]|(hbuf[5]<<16);  uh0.w = hbuf[6]|(hbuf[7]<<16);
        uh1.x = hbuf[8]|(hbuf[9]<<16);  uh1.y = hbuf[10]|(hbuf[11]<<16);
        uh1.z = hbuf[12]|(hbuf[13]<<16);uh1.w = hbuf[14]|(hbuf[15]<<16);
        ul0.x = lbuf[0]|(lbuf[1]<<16);  ul0.y = lbuf[2]|(lbuf[3]<<16);
        ul0.z = lbuf[4]|(lbuf[5]<<16);  ul0.w = lbuf[6]|(lbuf[7]<<16);
        ul1.x = lbuf[8]|(lbuf[9]<<16);  ul1.y = lbuf[10]|(lbuf[11]<<16);
        ul1.z = lbuf[12]|(lbuf[13]<<16);ul1.w = lbuf[14]|(lbuf[15]<<16);
        *(uint4*)&vthi[rowb + tl0]     = uh0;
        *(uint4*)&vthi[rowb + tl0 + 8] = uh1;
        *(uint4*)&vtlo[rowb + tl0]     = ul0;
        *(uint4*)&vtlo[rowb + tl0 + 8] = ul1;
    }
}

// ------------------------------------- flash attention, fp16x2 MFMA
__global__ __launch_bounds__(256) void attn_f16x2_kernel(
        const _Float16* __restrict__ qh, const _Float16* __restrict__ ql,
        const _Float16* __restrict__ kh, const _Float16* __restrict__ kl,
        const _Float16* __restrict__ vth, const _Float16* __restrict__ vtl,
        _Float16* __restrict__ oh, _Float16* __restrict__ ol) {
    __shared__ _Float16 Qh[64][72], Ql[64][72];
    __shared__ _Float16 Kh[64][72], Kl[64][72];
    __shared__ _Float16 Vh[64][72], Vl[64][72];
    __shared__ _Float16 Ph[64][72], Pl[64][72];
    int blk = blockIdx.x;
    int qt = blk & 15, bh = blk >> 4;
    int b = bh >> 3, hh = bh & 7;
    int q0 = qt << 6;
    int t = threadIdx.x;
    int w = t >> 6, lane = t & 63;
    int m16 = lane & 15, quad = lane >> 4;
    size_t bbase = (size_t)b * NVAR;
    size_t vbase = (size_t)bh * DH * NVAR;

    for (int idx = t; idx < 512; idx += 256) {
        int r = idx >> 3, cg = (idx & 7) << 3;
        size_t g = (bbase + q0 + r)*DM + hh*DH + cg;
        *(uint4*)&Qh[r][cg] = *(const uint4*)&qh[g];
        *(uint4*)&Ql[r][cg] = *(const uint4*)&ql[g];
    }
    float mrow[4] = {-1e30f,-1e30f,-1e30f,-1e30f};
    float lrow[4] = {0.f,0.f,0.f,0.f};
    f32x4 o1[4] = {}, o2[4] = {};

    for (int n0 = 0; n0 < NVAR; n0 += 64) {
        for (int idx = t; idx < 512; idx += 256) {
            int r = idx >> 3, cg = (idx & 7) << 3;
            size_t gk = (bbase + n0 + r)*DM + hh*DH + cg;
            size_t gv = vbase + (size_t)r*NVAR + n0 + cg;
            *(uint4*)&Kh[r][cg] = *(const uint4*)&kh[gk];
            *(uint4*)&Kl[r][cg] = *(const uint4*)&kl[gk];
            *(uint4*)&Vh[r][cg] = *(const uint4*)&vth[gv];
            *(uint4*)&Vl[r][cg] = *(const uint4*)&vtl[gv];
        }
        __syncthreads();

        f32x4 s1[4] = {}, s2[4] = {};
#pragma unroll
        for (int ks = 0; ks < 2; ++ks) {
            f16x8 ah = *(const f16x8*)&Qh[w*16 + m16][ks*32 + quad*8];
            f16x8 al = *(const f16x8*)&Ql[w*16 + m16][ks*32 + quad*8];
#pragma unroll
            for (int nt = 0; nt < 4; ++nt) {
                f16x8 bh_ = *(const f16x8*)&Kh[nt*16 + m16][ks*32 + quad*8];
                f16x8 bl_ = *(const f16x8*)&Kl[nt*16 + m16][ks*32 + quad*8];
                s1[nt] = MFMA16(ah, bh_, s1[nt], 0, 0, 0);
                s2[nt] = MFMA16(ah, bl_, s2[nt], 0, 0, 0);
                s2[nt] = MFMA16(al, bh_, s2[nt], 0, 0, 0);
            }
        }

        float pbuf[4][4];
#pragma unroll
        for (int r = 0; r < 4; ++r) {
            float sv0 = (s1[0][r] + s2[0][r]*ILSC)*0.125f;
            float sv1 = (s1[1][r] + s2[1][r]*ILSC)*0.125f;
            float sv2 = (s1[2][r] + s2[2][r]*ILSC)*0.125f;
            float sv3 = (s1[3][r] + s2[3][r]*ILSC)*0.125f;
            float mx = fmaxf(fmaxf(sv0, sv1), fmaxf(sv2, sv3));
            mx = fmaxf(mx, __shfl_xor(mx, 1));
            mx = fmaxf(mx, __shfl_xor(mx, 2));
            mx = fmaxf(mx, __shfl_xor(mx, 4));
            mx = fmaxf(mx, __shfl_xor(mx, 8));
            float mnew = fmaxf(mrow[r], mx);
            float alpha = __expf(mrow[r] - mnew);
            float p0 = __expf(sv0 - mnew), p1 = __expf(sv1 - mnew);
            float p2 = __expf(sv2 - mnew), p3 = __expf(sv3 - mnew);
            float rs = p0 + p1 + p2 + p3;
            rs += __shfl_xor(rs, 1);
            rs += __shfl_xor(rs, 2);
            rs += __shfl_xor(rs, 4);
            rs += __shfl_xor(rs, 8);
            lrow[r] = lrow[r]*alpha + rs;
            mrow[r] = mnew;
            pbuf[0][r] = p0; pbuf[1][r] = p1; pbuf[2][r] = p2; pbuf[3][r] = p3;
#pragma unroll
            for (int nt = 0; nt < 4; ++nt) { o1[nt][r] *= alpha; o2[nt][r] *= alpha; }
        }
#pragma unroll
        for (int nt = 0; nt < 4; ++nt)
#pragma unroll
            for (int r = 0; r < 4; ++r) {
                _Float16 h_, l_; fsplit(pbuf[nt][r], h_, l_);
                Ph[w*16 + quad*4 + r][nt*16 + m16] = h_;
                Pl[w*16 + quad*4 + r][nt*16 + m16] = l_;
            }
        __syncthreads();

#pragma unroll
        for (int ks = 0; ks < 2; ++ks) {
            f16x8 ph = *(const f16x8*)&Ph[w*16 + m16][ks*32 + quad*8];
            f16x8 pl = *(const f16x8*)&Pl[w*16 + m16][ks*32 + quad*8];
#pragma unroll
            for (int nt = 0; nt < 4; ++nt) {
                f16x8 vh_ = *(const f16x8*)&Vh[nt*16 + m16][ks*32 + quad*8];
                f16x8 vl_ = *(const f16x8*)&Vl[nt*16 + m16][ks*32 + quad*8];
                o1[nt] = MFMA16(ph, vh_, o1[nt], 0, 0, 0);
                o2[nt] = MFMA16(ph, vl_, o2[nt], 0, 0, 0);
                o2[nt] = MFMA16(pl, vh_, o2[nt], 0, 0, 0);
            }
        }
        __syncthreads();
    }
#pragma unroll
    for (int r = 0; r < 4; ++r) {
        float inv = 1.0f / lrow[r];
        size_t rowp = (bbase + q0 + w*16 + quad*4 + r)*DM + hh*DH;
#pragma unroll
        for (int nt = 0; nt < 4; ++nt) {
            float ov = (o1[nt][r] + o2[nt][r]*ILSC) * inv;
            _Float16 h_, l_; fsplit(ov, h_, l_);
            oh[rowp + nt*16 + m16] = h_;
            ol[rowp + nt*16 + m16] = l_;
        }
    }
}

// ---------------------------------------------------------------- LayerNorm
__global__ __launch_bounds__(256) void ln_kernel(
        _Float16* __restrict__ hhi, _Float16* __restrict__ hlo,
        const float* __restrict__ res,
        const float* __restrict__ w, const float* __restrict__ b) {
    int rowi = blockIdx.x, t = threadIdx.x;
    size_t base = (size_t)rowi * DM;
    float v0 = frec(hhi[base + t], hlo[base + t]);
    float v1 = frec(hhi[base + t + 256], hlo[base + t + 256]);
    if (res) { v0 += res[base + t]; v1 += res[base + t + 256]; }
    __shared__ float rs[256], rq[256];
    rs[t] = v0 + v1; rq[t] = v0*v0 + v1*v1;
    __syncthreads();
    for (int off = 128; off > 0; off >>= 1) {
        if (t < off) { rs[t] += rs[t+off]; rq[t] += rq[t+off]; }
        __syncthreads();
    }
    float m = rs[0] / (float)DM;
    float var = rq[0] / (float)DM - m*m;
    float inv = 1.0f / sqrtf(var + LN_EPS);
    float y0 = (v0 - m)*inv * w[t]       + b[t];
    float y1 = (v1 - m)*inv * w[t + 256] + b[t + 256];
    _Float16 h0, l0, h1, l1;
    fsplit(y0, h0, l0); fsplit(y1, h1, l1);
    hhi[base + t] = h0;       hlo[base + t] = l0;
    hhi[base + t + 256] = h1; hlo[base + t + 256] = l1;
}

__device__ __forceinline__ float gelu_exact(float xv) {
    return 0.5f * xv * (1.0f + erff(xv * 0.70710678118654752f));
}

// ---------------------------------------------------------------- MoE FFN
__global__ __launch_bounds__(256) void moe_kernel(
        const _Float16* __restrict__ hhi, const _Float16* __restrict__ hlo,
        float* __restrict__ out,
        const float* __restrict__ gW, const float* __restrict__ W1, const float* __restrict__ b1,
        const float* __restrict__ W2, const float* __restrict__ b2) {
    int tok = blockIdx.x, t = threadIdx.x;
    __shared__ float hs[DM];
    __shared__ float red[32][8];
    __shared__ float glog[8];
    __shared__ float hmid[8];
    __shared__ float wsel[2];
    __shared__ int   esel[2];
    size_t base = (size_t)tok * DM;
    hs[t] = frec(hhi[base + t], hlo[base + t]);
    hs[t + 256] = frec(hhi[base + t + 256], hlo[base + t + 256]);
    __syncthreads();
    int e = t & 7, i0 = t >> 3;
    {
        float a = 0.f;
        for (int i = i0; i < DM; i += 32) a += hs[i] * gW[i*NE + e];
        red[i0][e] = a;
    }
    __syncthreads();
    if (t < 8) { float sv = 0.f; for (int i = 0; i < 32; ++i) sv += red[i][t]; glog[t] = sv; }
    __syncthreads();
    if (t == 0) {
        float m0 = -1e30f, m1 = -1e30f; int s0i = 0, s1i = 0;
        for (int ei = 0; ei < 8; ++ei) {
            float vv = glog[ei];
            if (vv > m0) { m1 = m0; s1i = s0i; m0 = vv; s0i = ei; }
            else if (vv > m1) { m1 = vv; s1i = ei; }
        }
        float Z = 0.f;
        for (int ei = 0; ei < 8; ++ei) Z += expf(glog[ei] - m0);
        wsel[0] = 1.0f / Z;
        wsel[1] = expf(m1 - m0) / Z;
        esel[0] = s0i; esel[1] = s1i;
    }
    __syncthreads();
    float o0 = 0.f, o1 = 0.f;
    for (int ks = 0; ks < 2; ++ks) {
        int ee = esel[ks]; float wk = wsel[ks];
        int f = t & 7;
        float a = 0.f;
        for (int i = i0; i < DM; i += 32) a += hs[i] * W1[((size_t)ee*DM + i)*NF + f];
        red[i0][f] = a;
        __syncthreads();
        if (t < 8) {
            float sv = b1[ee*NF + t];
            for (int i = 0; i < 32; ++i) sv += red[i][t];
            hmid[t] = gelu_exact(sv);
        }
        __syncthreads();
        float s0v = b2[ee*DM + t], s1v = b2[ee*DM + t + 256];
#pragma unroll
        for (int i = 0; i < NF; ++i) {
            float hm = hmid[i];
            const float* wp = W2 + ((size_t)ee*NF + i)*DM;
            s0v += hm * wp[t]; s1v += hm * wp[t + 256];
        }
        o0 += wk * s0v; o1 += wk * s1v;
        __syncthreads();
    }
    out[base + t] = o0; out[base + t + 256] = o1;
}

// ------------------------------------------------------------- head: init
__global__ __launch_bounds__(64) void head_init_kernel(int* __restrict__ cnt) {
    if (threadIdx.x < NE) cnt[threadIdx.x] = 0;
}

// ------------------------------------------------------------- head: gate
// One block per token: coalesced LDS staging of h, 8 gate logits, top-2.
// Also zeroes outacc row (coalesced).  No atomics here.
__global__ __launch_bounds__(256) void head_gate_kernel(
        const _Float16* __restrict__ hhi, const _Float16* __restrict__ hlo,
        const float* __restrict__ gW,
        int* __restrict__ sel, float2* __restrict__ wpair,
        float* __restrict__ outacc) {
    int tok = blockIdx.x, t = threadIdx.x;
    __shared__ float hs[DM];
    __shared__ float red[32][8];
    __shared__ float glog[8];
    size_t base = (size_t)tok * DM;
    hs[t] = frec(hhi[base + t], hlo[base + t]);
    hs[t + 256] = frec(hhi[base + t + 256], hlo[base + t + 256]);
    outacc[base + t] = 0.f; outacc[base + t + 256] = 0.f;
    __syncthreads();
    int e = t & 7, i0 = t >> 3;
    float a = 0.f;
    for (int i = i0; i < DM; i += 32) a += hs[i] * gW[i*NE + e];
    red[i0][e] = a;
    __syncthreads();
    if (t < 8) { float sv = 0.f; for (int i = 0; i < 32; ++i) sv += red[i][t]; glog[t] = sv; }
    __syncthreads();
    if (t == 0) {
        float m0 = -1e30f, m1 = -1e30f; int s0i = 0, s1i = 0;
        for (int ei = 0; ei < 8; ++ei) {
            float vv = glog[ei];
            if (vv > m0) { m1 = m0; s1i = s0i; m0 = vv; s0i = ei; }
            else if (vv > m1) { m1 = vv; s1i = ei; }
        }
        float Z = 0.f;
        for (int ei = 0; ei < 8; ++ei) Z += __expf(glog[ei] - m0);
        float2 wv;
        wv.x = 1.0f / Z;
        wv.y = __expf(m1 - m0) / Z;
        sel[tok] = s0i | (s1i << 3);
        wpair[tok] = wv;
    }
}

// ------------------------------------------------------------- head: bucket
// One wave per 64 tokens; ballot-aggregated inserts: 1 atomic per (wave,expert).
__global__ __launch_bounds__(64) void head_bucket_kernel(
        const int* __restrict__ sel, const float2* __restrict__ wpair,
        int* __restrict__ cnt, int* __restrict__ idxlist, float* __restrict__ wlist) {
    int lane = threadIdx.x;
    int tok = blockIdx.x*64 + lane;
    int s = sel[tok];
    int s0 = s & 7, s1 = (s >> 3) & 7;
    float2 wv = wpair[tok];
    unsigned long long lmask = (lane == 63) ? 0x7FFFFFFFFFFFFFFFull
                                            : ((1ull << lane) - 1ull);
#pragma unroll
    for (int e = 0; e < NE; ++e) {
        unsigned long long m0 = __ballot(s0 == e);
        unsigned long long m1 = __ballot(s1 == e);
        int tot = __popcll(m0) + __popcll(m1);
        int basep = 0;
        if (lane == 0 && tot > 0) basep = atomicAdd(&cnt[e], tot);
        basep = __shfl(basep, 0);
        if (s0 == e) {
            int p = basep + __popcll(m0 & lmask);
            idxlist[e*NTOK + p] = tok; wlist[e*NTOK + p] = wv.x;
        }
        if (s1 == e) {
            int p = basep + __popcll(m0) + __popcll(m1 & lmask);
            idxlist[e*NTOK + p] = tok; wlist[e*NTOK + p] = wv.y;
        }
    }
}

// ------------------------------------------------------------- head: grouped GEMM
__global__ __launch_bounds__(256) void head_gemm_kernel(
        const _Float16* __restrict__ hhi, const _Float16* __restrict__ hlo,
        const float* __restrict__ HW, const float* __restrict__ Hb,
        const int* __restrict__ cnt, const int* __restrict__ idxlist,
        const float* __restrict__ wlist, float* __restrict__ outacc) {
    int e = blockIdx.z;
    int cnt_e = cnt[e];
    int m0 = blockIdx.y << 6;
    if (m0 >= cnt_e) return;
    int rv = cnt_e - m0; if (rv > 64) rv = 64;
    int bn = blockIdx.x << 6;
    int t = threadIdx.x;

    __shared__ float As[16][65];
    __shared__ float Bs[16][64];
    __shared__ int   idxs[64];
    __shared__ float ws[64];
    if (t < 64) {
        if (t < rv) { idxs[t] = idxlist[e*NTOK + m0 + t]; ws[t] = wlist[e*NTOK + m0 + t]; }
        else        { idxs[t] = idxlist[e*NTOK + m0];     ws[t] = 0.f; }
    }
    __syncthreads();

    const float* W = HW + (size_t)e*DM*DM;
    int tx = t & 15, ty = t >> 4;
    int arow = t >> 4, acol = t & 15;
    int bcol = t & 63, brow = t >> 6;
    float acc[4][4] = {};
    for (int k0 = 0; k0 < DM; k0 += 16) {
#pragma unroll
        for (int r = 0; r < 4; ++r) {
            size_t g = (size_t)idxs[arow + 16*r]*DM + k0 + acol;
            As[acol][arow + 16*r] = frec(hhi[g], hlo[g]);
        }
#pragma unroll
        for (int r = 0; r < 4; ++r)
            Bs[brow + 4*r][bcol] = W[(size_t)(k0 + brow + 4*r)*DM + bn + bcol];
        __syncthreads();
#pragma unroll
        for (int kk = 0; kk < 16; ++kk) {
            float a0 = As[kk][ty*4+0], a1 = As[kk][ty*4+1];
            float a2 = As[kk][ty*4+2], a3 = As[kk][ty*4+3];
            float b0 = Bs[kk][tx*4+0], b1 = Bs[kk][tx*4+1];
            float b2 = Bs[kk][tx*4+2], b3 = Bs[kk][tx*4+3];
            acc[0][0] += a0*b0; acc[0][1] += a0*b1; acc[0][2] += a0*b2; acc[0][3] += a0*b3;
            acc[1][0] += a1*b0; acc[1][1] += a1*b1; acc[1][2] += a1*b2; acc[1][3] += a1*b3;
            acc[2][0] += a2*b0; acc[2][1] += a2*b1; acc[2][2] += a2*b2; acc[2][3] += a2*b3;
            acc[3][0] += a3*b0; acc[3][1] += a3*b1; acc[3][2] += a3*b2; acc[3][3] += a3*b3;
        }
        __syncthreads();
    }
#pragma unroll
    for (int i = 0; i < 4; ++i) {
        int rloc = ty*4 + i;
        if (rloc < rv) {
            float wk = ws[rloc];
            size_t base = (size_t)idxs[rloc]*DM;
#pragma unroll
            for (int jj = 0; jj < 4; ++jj) {
                int col = bn + tx*4 + jj;
                atomicAdd(&outacc[base + col], wk*(acc[i][jj] + Hb[e*DM + col]));
            }
        }
    }
}

// ------------------------------------------------------------- head: denorm
__global__ __launch_bounds__(256) void head_denorm_kernel(
        const float* __restrict__ outacc,
        const float* __restrict__ rw, const float* __restrict__ rb,
        const float* __restrict__ mean, const float* __restrict__ stdd,
        float* __restrict__ out) {
    int tok = blockIdx.x, t = threadIdx.x;
    int n = tok & (NVAR - 1);
    size_t base = (size_t)tok * DM;
    float mn = mean[tok], sd = stdd[tok];
    float rwv = rw[n] + 1e-10f, rbv = rb[n];
    float o0 = outacc[base + t], o1 = outacc[base + t + 256];
    out[base + t]       = (o0 - rbv) / rwv * sd + mn;
    out[base + t + 256] = (o1 - rbv) / rwv * sd + mn;
}

// ---------------------------------------------------------------- launch
extern "C" void kernel_launch(void* const* d_in, const int* in_sizes, int n_in,
                              void* d_out, int out_size, void* d_ws, size_t ws_size,
                              hipStream_t stream) {
    const float* x       = (const float*)d_in[0];
    const float* revin_w = (const float*)d_in[1];
    const float* revin_b = (const float*)d_in[2];
    const float* emb_W   = (const float*)d_in[3];
    const float* emb_b   = (const float*)d_in[4];
    const float* Wq      = (const float*)d_in[5];
    const float* bq      = (const float*)d_in[6];
    const float* Wk      = (const float*)d_in[7];
    const float* bk      = (const float*)d_in[8];
    const float* Wv      = (const float*)d_in[9];
    const float* bv      = (const float*)d_in[10];
    const float* Wo      = (const float*)d_in[11];
    const float* bo      = (const float*)d_in[12];
    const float* ln1_w   = (const float*)d_in[13];
    const float* ln1_b   = (const float*)d_in[14];
    const float* ln2_w   = (const float*)d_in[15];
    const float* ln2_b   = (const float*)d_in[16];
    const float* gate_W  = (const float*)d_in[17];
    const float* eW1     = (const float*)d_in[18];
    const float* eb1     = (const float*)d_in[19];
    const float* eW2     = (const float*)d_in[20];
    const float* eb2     = (const float*)d_in[21];
    const float* enc_w   = (const float*)d_in[22];
    const float* enc_b   = (const float*)d_in[23];
    const float* hgW     = (const float*)d_in[24];
    const float* hW      = (const float*)d_in[25];
    const float* hb      = (const float*)d_in[26];
    float* out = (float*)d_out;

    const size_t TOKD = (size_t)NTOK * DM;   // 4194304
    float* ws   = (float*)d_ws;
    float* mean = ws;
    float* stdd = ws + 8192;
    _Float16* hhi  = (_Float16*)(ws + 16384);
    _Float16* hlo  = hhi + TOKD;
    _Float16* qhi  = hlo + TOKD;     // also xn planes, attn O planes, head outacc (fp32 raw)
    _Float16* qlo  = qhi + TOKD;
    _Float16* khi  = qlo + TOKD;     // also proj fp32 raw
    _Float16* klo  = khi + TOKD;
    _Float16* vthi = klo + TOKD;
    _Float16* vtlo = vthi + TOKD;
    _Float16* whi  = vtlo + TOKD;    // 9 transposed split weights
    _Float16* wlo  = whi + (size_t)9*DM*DM;
    int*   cnt     = (int*)(wlo + (size_t)9*DM*DM);
    int*   idxlist = cnt + 16;
    float* wlist   = (float*)(idxlist + NE*NTOK);
    int*   sel     = (int*)(wlist + NE*NTOK);
    float2* wpair  = (float2*)(sel + NTOK);
    float* proj    = (float*)khi;
    float* outacc  = (float*)qhi;

    dim3 blk(256);
    dim3 ggemm(DM/64, NTOK/128);     // (8, 64)

    revin_stats_kernel<<<dim3(BATCH*16), blk, 0, stream>>>(x, mean, stdd);
    revin_norm_kernel<<<dim3(NVAR/32, SEQ/32, BATCH), blk, 0, stream>>>(
        x, mean, stdd, revin_w, revin_b, qhi, qlo);

    WSrcs srcs;
    srcs.p[0] = emb_W;
    for (int l = 0; l < NL; ++l) {
        srcs.p[1 + l*4 + 0] = Wq + (size_t)l*DM*DM;
        srcs.p[1 + l*4 + 1] = Wk + (size_t)l*DM*DM;
        srcs.p[1 + l*4 + 2] = Wv + (size_t)l*DM*DM;
        srcs.p[1 + l*4 + 3] = Wo + (size_t)l*DM*DM;
    }
    transpose_w_kernel<<<dim3(8, 8, 9), blk, 0, stream>>>(srcs, whi, wlo);

    gemm_f16x2_kernel<<<ggemm, blk, 0, stream>>>(
        qhi, qlo, whi, wlo, emb_b, nullptr, hhi, hlo, NTOK, SEQ, DM);

    for (int l = 0; l < NL; ++l) {
        size_t oq = (size_t)(1 + l*4 + 0)*DM*DM;
        size_t ok = (size_t)(1 + l*4 + 1)*DM*DM;
        size_t ov = (size_t)(1 + l*4 + 2)*DM*DM;
        size_t oo = (size_t)(1 + l*4 + 3)*DM*DM;
        gemm_f16x2_kernel<<<ggemm, blk, 0, stream>>>(
            hhi, hlo, whi + oq, wlo + oq, bq + l*DM, nullptr, qhi, qlo, NTOK, DM, DM);
        gemm_f16x2_kernel<<<ggemm, blk, 0, stream>>>(
            hhi, hlo, whi + ok, wlo + ok, bk + l*DM, nullptr, khi, klo, NTOK, DM, DM);
        gemm_f16x2_vt_kernel<<<ggemm, blk, 0, stream>>>(
            hhi, hlo, whi + ov, wlo + ov, bv + l*DM, vthi, vtlo);
        attn_f16x2_kernel<<<dim3(64*16), blk, 0, stream>>>(
            qhi, qlo, khi, klo, vthi, vtlo, qhi, qlo);
        gemm_f16x2_kernel<<<ggemm, blk, 0, stream>>>(
            qhi, qlo, whi + oo, wlo + oo, bo + l*DM, proj, nullptr, nullptr, NTOK, DM, DM);
        ln_kernel<<<dim3(NTOK), blk, 0, stream>>>(hhi, hlo, proj, ln1_w + l*DM, ln1_b + l*DM);
        moe_kernel<<<dim3(NTOK), blk, 0, stream>>>(
            hhi, hlo, proj, gate_W + (size_t)l*DM*NE,
            eW1 + (size_t)l*NE*DM*NF, eb1 + (size_t)l*NE*NF,
            eW2 + (size_t)l*NE*NF*DM, eb2 + (size_t)l*NE*DM);
        ln_kernel<<<dim3(NTOK), blk, 0, stream>>>(hhi, hlo, proj, ln2_w + l*DM, ln2_b + l*DM);
    }

    ln_kernel<<<dim3(NTOK), blk, 0, stream>>>(hhi, hlo, nullptr, enc_w, enc_b);

    head_init_kernel<<<dim3(1), dim3(64), 0, stream>>>(cnt);
    head_gate_kernel<<<dim3(NTOK), blk, 0, stream>>>(hhi, hlo, hgW, sel, wpair, outacc);
    head_bucket_kernel<<<dim3(NTOK/64), dim3(64), 0, stream>>>(sel, wpair, cnt, idxlist, wlist);
    head_gemm_kernel<<<dim3(DM/64, NTOK/64, NE), blk, 0, stream>>>(
        hhi, hlo, hW, hb, cnt, idxlist, wlist, outacc);
    head_denorm_kernel<<<dim3(NTOK), blk, 0, stream>>>(
        outacc, revin_w, revin_b, mean, stdd, out);
}

// Round 7
// 1024.060 us; speedup vs baseline: 6.9357x; 1.0530x over previous
//
#include <hip/hip_runtime.h>
#include <math.h>

#define BATCH 8
#define SEQ 512
#define NVAR 1024
#define DM 512
#define NH 8
#define DH 64
#define NE 8
#define NF 8
#define NL 2
#define NTOK (BATCH*NVAR)   // 8192
#define LN_EPS 1e-5f
#define LSC 2048.0f
#define ILSC (1.0f/2048.0f)

typedef __attribute__((ext_vector_type(8))) _Float16 f16x8;
typedef __attribute__((ext_vector_type(4))) float f32x4;
#define MFMA16 __builtin_amdgcn_mfma_f32_16x16x32_f16

__device__ __forceinline__ void fsplit(float v, _Float16& hi, _Float16& lo) {
    hi = (_Float16)v;
    lo = (_Float16)((v - (float)hi) * LSC);
}
__device__ __forceinline__ float frec(_Float16 hi, _Float16 lo) {
    return (float)hi + (float)lo * ILSC;
}

// ---------------------------------------------------------------- RevIN stats
__global__ __launch_bounds__(256) void revin_stats_kernel(
        const float* __restrict__ x, float* __restrict__ mean, float* __restrict__ stdd) {
    int blk = blockIdx.x;            // b*16 + ntile
    int b = blk >> 4;
    int n0 = (blk & 15) << 6;
    int t = threadIdx.x;
    int ni = t & 63, sg = t >> 6;
    float s = 0.f, ss = 0.f;
    for (int sidx = sg; sidx < SEQ; sidx += 4) {
        float v = x[((size_t)b*SEQ + sidx)*NVAR + n0 + ni];
        s += v; ss += v*v;
    }
    __shared__ float rs[4][64], rq[4][64];
    rs[sg][ni] = s; rq[sg][ni] = ss;
    __syncthreads();
    if (t < 64) {
        float su = rs[0][t] + rs[1][t] + rs[2][t] + rs[3][t];
        float sq = rq[0][t] + rq[1][t] + rq[2][t] + rq[3][t];
        float m  = su / (float)SEQ;
        float var = sq / (float)SEQ - m*m;
        int n = n0 + t;
        mean[b*NVAR + n] = m;
        stdd[b*NVAR + n] = sqrtf(var + LN_EPS);
    }
}

// ------------------------------- RevIN normalize + transpose (split f16 out)
__global__ __launch_bounds__(256) void revin_norm_kernel(
        const float* __restrict__ x, const float* __restrict__ mean, const float* __restrict__ stdd,
        const float* __restrict__ rw, const float* __restrict__ rb,
        _Float16* __restrict__ xnhi, _Float16* __restrict__ xnlo) {
    __shared__ float tile[32][33];
    int n0 = blockIdx.x << 5, s0 = blockIdx.y << 5, b = blockIdx.z;
    int t = threadIdx.x;
    int j = t & 31, i0 = t >> 5;
    for (int ii = i0; ii < 32; ii += 8)
        tile[ii][j] = x[((size_t)b*SEQ + s0 + ii)*NVAR + n0 + j];
    __syncthreads();
    int si = t & 31, j0 = t >> 5;
    for (int nj = j0; nj < 32; nj += 8) {
        int n = n0 + nj;
        float m = mean[b*NVAR + n], sd = stdd[b*NVAR + n];
        float v = (tile[si][nj] - m) / sd * rw[n] + rb[n];
        _Float16 h_, l_; fsplit(v, h_, l_);
        size_t idx = ((size_t)b*NVAR + n)*SEQ + s0 + si;
        xnhi[idx] = h_; xnlo[idx] = l_;
    }
}

// ----------------------- weight transpose+split: [K,N] -> [N,K] f16 hi/lo
struct WSrcs { const float* p[9]; };
__global__ __launch_bounds__(256) void transpose_w_kernel(
        WSrcs srcs, _Float16* __restrict__ whi, _Float16* __restrict__ wlo) {
    const float* W = srcs.p[blockIdx.z];
    _Float16* oh = whi + (size_t)blockIdx.z * DM * DM;
    _Float16* ol = wlo + (size_t)blockIdx.z * DM * DM;
    __shared__ float tile[64][65];
    int k0 = blockIdx.x << 6, n0 = blockIdx.y << 6;
    int t = threadIdx.x;
    for (int idx = t; idx < 4096; idx += 256) {
        int k = idx >> 6, n = idx & 63;
        tile[k][n] = W[(size_t)(k0 + k)*DM + n0 + n];
    }
    __syncthreads();
    for (int idx = t; idx < 4096; idx += 256) {
        int n = idx >> 6, k = idx & 63;
        _Float16 h_, l_; fsplit(tile[k][n], h_, l_);
        size_t o = (size_t)(n0 + n)*DM + k0 + k;
        oh[o] = h_; ol[o] = l_;
    }
}

// ------------------------------------------- fp16x2 MFMA GEMM (fp32-grade)
// C[M,N] = A[M,K] @ Wt[N,K]^T + bias, A/W given as hi/lo f16 planes.
// 128x64 tile, BK=32, 4 waves; wave owns 32 rows (2 x 16).
__global__ __launch_bounds__(256) void gemm_f16x2_kernel(
        const _Float16* __restrict__ Ahg, const _Float16* __restrict__ Alg,
        const _Float16* __restrict__ Whg, const _Float16* __restrict__ Wlg,
        const float* __restrict__ bias, float* __restrict__ C,
        _Float16* __restrict__ Chi, _Float16* __restrict__ Clo,
        int M, int K, int N) {
    __shared__ _Float16 sAh[128][40], sAl[128][40];
    __shared__ _Float16 sBh[64][40],  sBl[64][40];
    int bm = blockIdx.y << 7, bn = blockIdx.x << 6;
    int t = threadIdx.x;
    int w = t >> 6, lane = t & 63, m16 = lane & 15, quad = lane >> 4;
    int ra = t >> 1,  ca = (t & 1) << 4;   // A: 128 rows x 2 groups of 16
    int rb = t >> 2,  cb = (t & 3) << 3;   // B: 64 rows x 4 groups of 8
    f32x4 a1[2][4] = {}, a2[2][4] = {};
    for (int k0 = 0; k0 < K; k0 += 32) {
        size_t ga = (size_t)(bm + ra)*K + k0 + ca;
        size_t gb = (size_t)(bn + rb)*K + k0 + cb;
        *(uint4*)&sAh[ra][ca]   = *(const uint4*)&Ahg[ga];
        *(uint4*)&sAh[ra][ca+8] = *(const uint4*)&Ahg[ga + 8];
        *(uint4*)&sAl[ra][ca]   = *(const uint4*)&Alg[ga];
        *(uint4*)&sAl[ra][ca+8] = *(const uint4*)&Alg[ga + 8];
        *(uint4*)&sBh[rb][cb]   = *(const uint4*)&Whg[gb];
        *(uint4*)&sBl[rb][cb]   = *(const uint4*)&Wlg[gb];
        __syncthreads();
        f16x8 bh_[4], bl_[4];
#pragma unroll
        for (int nt = 0; nt < 4; ++nt) {
            bh_[nt] = *(const f16x8*)&sBh[nt*16 + m16][quad*8];
            bl_[nt] = *(const f16x8*)&sBl[nt*16 + m16][quad*8];
        }
#pragma unroll
        for (int h2 = 0; h2 < 2; ++h2) {
            f16x8 ah = *(const f16x8*)&sAh[w*32 + h2*16 + m16][quad*8];
            f16x8 al = *(const f16x8*)&sAl[w*32 + h2*16 + m16][quad*8];
#pragma unroll
            for (int nt = 0; nt < 4; ++nt) {
                a1[h2][nt] = MFMA16(ah, bh_[nt], a1[h2][nt], 0, 0, 0);
                a2[h2][nt] = MFMA16(ah, bl_[nt], a2[h2][nt], 0, 0, 0);
                a2[h2][nt] = MFMA16(al, bh_[nt], a2[h2][nt], 0, 0, 0);
            }
        }
        __syncthreads();
    }
#pragma unroll
    for (int h2 = 0; h2 < 2; ++h2)
#pragma unroll
        for (int nt = 0; nt < 4; ++nt) {
            int col = bn + nt*16 + m16;
            float bv = bias[col];
#pragma unroll
            for (int r = 0; r < 4; ++r) {
                size_t row = bm + w*32 + h2*16 + quad*4 + r;
                float v = a1[h2][nt][r] + a2[h2][nt][r]*ILSC + bv;
                if (C) C[row*N + col] = v;
                if (Chi) {
                    _Float16 h_, l_; fsplit(v, h_, l_);
                    Chi[row*N + col] = h_; Clo[row*N + col] = l_;
                }
            }
        }
}

// ------------------- fp16x2 GEMM, transposed split output (V projection)
// out: vthi/vtlo [b*8+h][dh(64)][tok(1024)]   M=NTOK, K=N=DM fixed.
__global__ __launch_bounds__(256) void gemm_f16x2_vt_kernel(
        const _Float16* __restrict__ Ahg, const _Float16* __restrict__ Alg,
        const _Float16* __restrict__ Whg, const _Float16* __restrict__ Wlg,
        const float* __restrict__ bias,
        _Float16* __restrict__ vthi, _Float16* __restrict__ vtlo) {
    __shared__ _Float16 sAh[128][40], sAl[128][40];
    __shared__ _Float16 sBh[64][40],  sBl[64][40];
    __shared__ float Ct[128][65];
    int bm = blockIdx.y << 7, bn = blockIdx.x << 6;
    int t = threadIdx.x;
    int w = t >> 6, lane = t & 63, m16 = lane & 15, quad = lane >> 4;
    int ra = t >> 1,  ca = (t & 1) << 4;
    int rb = t >> 2,  cb = (t & 3) << 3;
    f32x4 a1[2][4] = {}, a2[2][4] = {};
    for (int k0 = 0; k0 < DM; k0 += 32) {
        size_t ga = (size_t)(bm + ra)*DM + k0 + ca;
        size_t gb = (size_t)(bn + rb)*DM + k0 + cb;
        *(uint4*)&sAh[ra][ca]   = *(const uint4*)&Ahg[ga];
        *(uint4*)&sAh[ra][ca+8] = *(const uint4*)&Ahg[ga + 8];
        *(uint4*)&sAl[ra][ca]   = *(const uint4*)&Alg[ga];
        *(uint4*)&sAl[ra][ca+8] = *(const uint4*)&Alg[ga + 8];
        *(uint4*)&sBh[rb][cb]   = *(const uint4*)&Whg[gb];
        *(uint4*)&sBl[rb][cb]   = *(const uint4*)&Wlg[gb];
        __syncthreads();
        f16x8 bh_[4], bl_[4];
#pragma unroll
        for (int nt = 0; nt < 4; ++nt) {
            bh_[nt] = *(const f16x8*)&sBh[nt*16 + m16][quad*8];
            bl_[nt] = *(const f16x8*)&sBl[nt*16 + m16][quad*8];
        }
#pragma unroll
        for (int h2 = 0; h2 < 2; ++h2) {
            f16x8 ah = *(const f16x8*)&sAh[w*32 + h2*16 + m16][quad*8];
            f16x8 al = *(const f16x8*)&sAl[w*32 + h2*16 + m16][quad*8];
#pragma unroll
            for (int nt = 0; nt < 4; ++nt) {
                a1[h2][nt] = MFMA16(ah, bh_[nt], a1[h2][nt], 0, 0, 0);
                a2[h2][nt] = MFMA16(ah, bl_[nt], a2[h2][nt], 0, 0, 0);
                a2[h2][nt] = MFMA16(al, bh_[nt], a2[h2][nt], 0, 0, 0);
            }
        }
        __syncthreads();
    }
#pragma unroll
    for (int h2 = 0; h2 < 2; ++h2)
#pragma unroll
        for (int nt = 0; nt < 4; ++nt) {
            float bv = bias[bn + nt*16 + m16];
#pragma unroll
            for (int r = 0; r < 4; ++r)
                Ct[w*32 + h2*16 + quad*4 + r][nt*16 + m16] = a1[h2][nt][r] + a2[h2][nt][r]*ILSC + bv;
        }
    __syncthreads();
    int b = bm >> 10, tokn0 = bm & 1023, hh = bn >> 6;
    int dh = t >> 2, tg = (t & 3) << 4;
    size_t rowb = ((size_t)(b*8 + hh)*64 + dh)*NVAR + tokn0;
    for (int hb = 0; hb < 2; ++hb) {
        int tl0 = hb*64 + tg;
        unsigned short hbuf[16], lbuf[16];
#pragma unroll
        for (int i = 0; i < 16; ++i) {
            _Float16 h_, l_; fsplit(Ct[tl0 + i][dh], h_, l_);
            hbuf[i] = __builtin_bit_cast(unsigned short, h_);
            lbuf[i] = __builtin_bit_cast(unsigned short, l_);
        }
        uint4 uh0, uh1, ul0, ul1;
        uh0.x = hbuf[0]|(hbuf[1]<<16);  uh0.y = hbuf[2]|(hbuf[3]<<16);
        uh0.z = hbuf[4]|(hbuf[5]<<16);  uh0.w = hbuf[6]|(hbuf[7]<<16);
        uh1.x = hbuf[8]|(hbuf[9]<<16);  uh1.y = hbuf[10]|(hbuf[11]<<16);
        uh1.z = hbuf[12]|(hbuf[13]<<16);uh1.w = hbuf[14]|(hbuf[15]<<16);
        ul0.x = lbuf[0]|(lbuf[1]<<16);  ul0.y = lbuf[2]|(lbuf[3]<<16);
        ul0.z = lbuf[4]|(lbuf[5]<<16);  ul0.w = lbuf[6]|(lbuf[7]<<16);
        ul1.x = lbuf[8]|(lbuf[9]<<16);  ul1.y = lbuf[10]|(lbuf[11]<<16);
        ul1.z = lbuf[12]|(lbuf[13]<<16);ul1.w = lbuf[14]|(lbuf[15]<<16);
        *(uint4*)&vthi[rowb + tl0]     = uh0;
        *(uint4*)&vthi[rowb + tl0 + 8] = uh1;
        *(uint4*)&vtlo[rowb + tl0]     = ul0;
        *(uint4*)&vtlo[rowb + tl0 + 8] = ul1;
    }
}

// ------------------------------------- flash attention, fp16x2 MFMA
__global__ __launch_bounds__(256) void attn_f16x2_kernel(
        const _Float16* __restrict__ qh, const _Float16* __restrict__ ql,
        const _Float16* __restrict__ kh, const _Float16* __restrict__ kl,
        const _Float16* __restrict__ vth, const _Float16* __restrict__ vtl,
        _Float16* __restrict__ oh, _Float16* __restrict__ ol) {
    __shared__ _Float16 Qh[64][72], Ql[64][72];
    __shared__ _Float16 Kh[64][72], Kl[64][72];
    __shared__ _Float16 Vh[64][72], Vl[64][72];
    __shared__ _Float16 Ph[64][72], Pl[64][72];
    int blk = blockIdx.x;
    int qt = blk & 15, bh = blk >> 4;
    int b = bh >> 3, hh = bh & 7;
    int q0 = qt << 6;
    int t = threadIdx.x;
    int w = t >> 6, lane = t & 63;
    int m16 = lane & 15, quad = lane >> 4;
    size_t bbase = (size_t)b * NVAR;
    size_t vbase = (size_t)bh * DH * NVAR;

    for (int idx = t; idx < 512; idx += 256) {
        int r = idx >> 3, cg = (idx & 7) << 3;
        size_t g = (bbase + q0 + r)*DM + hh*DH + cg;
        *(uint4*)&Qh[r][cg] = *(const uint4*)&qh[g];
        *(uint4*)&Ql[r][cg] = *(const uint4*)&ql[g];
    }
    float mrow[4] = {-1e30f,-1e30f,-1e30f,-1e30f};
    float lrow[4] = {0.f,0.f,0.f,0.f};
    f32x4 o1[4] = {}, o2[4] = {};

    for (int n0 = 0; n0 < NVAR; n0 += 64) {
        for (int idx = t; idx < 512; idx += 256) {
            int r = idx >> 3, cg = (idx & 7) << 3;
            size_t gk = (bbase + n0 + r)*DM + hh*DH + cg;
            size_t gv = vbase + (size_t)r*NVAR + n0 + cg;
            *(uint4*)&Kh[r][cg] = *(const uint4*)&kh[gk];
            *(uint4*)&Kl[r][cg] = *(const uint4*)&kl[gk];
            *(uint4*)&Vh[r][cg] = *(const uint4*)&vth[gv];
            *(uint4*)&Vl[r][cg] = *(const uint4*)&vtl[gv];
        }
        __syncthreads();

        f32x4 s1[4] = {}, s2[4] = {};
#pragma unroll
        for (int ks = 0; ks < 2; ++ks) {
            f16x8 ah = *(const f16x8*)&Qh[w*16 + m16][ks*32 + quad*8];
            f16x8 al = *(const f16x8*)&Ql[w*16 + m16][ks*32 + quad*8];
#pragma unroll
            for (int nt = 0; nt < 4; ++nt) {
                f16x8 bh_ = *(const f16x8*)&Kh[nt*16 + m16][ks*32 + quad*8];
                f16x8 bl_ = *(const f16x8*)&Kl[nt*16 + m16][ks*32 + quad*8];
                s1[nt] = MFMA16(ah, bh_, s1[nt], 0, 0, 0);
                s2[nt] = MFMA16(ah, bl_, s2[nt], 0, 0, 0);
                s2[nt] = MFMA16(al, bh_, s2[nt], 0, 0, 0);
            }
        }

        float pbuf[4][4];
#pragma unroll
        for (int r = 0; r < 4; ++r) {
            float sv0 = (s1[0][r] + s2[0][r]*ILSC)*0.125f;
            float sv1 = (s1[1][r] + s2[1][r]*ILSC)*0.125f;
            float sv2 = (s1[2][r] + s2[2][r]*ILSC)*0.125f;
            float sv3 = (s1[3][r] + s2[3][r]*ILSC)*0.125f;
            float mx = fmaxf(fmaxf(sv0, sv1), fmaxf(sv2, sv3));
            mx = fmaxf(mx, __shfl_xor(mx, 1));
            mx = fmaxf(mx, __shfl_xor(mx, 2));
            mx = fmaxf(mx, __shfl_xor(mx, 4));
            mx = fmaxf(mx, __shfl_xor(mx, 8));
            float mnew = fmaxf(mrow[r], mx);
            float alpha = __expf(mrow[r] - mnew);
            float p0 = __expf(sv0 - mnew), p1 = __expf(sv1 - mnew);
            float p2 = __expf(sv2 - mnew), p3 = __expf(sv3 - mnew);
            float rs = p0 + p1 + p2 + p3;
            rs += __shfl_xor(rs, 1);
            rs += __shfl_xor(rs, 2);
            rs += __shfl_xor(rs, 4);
            rs += __shfl_xor(rs, 8);
            lrow[r] = lrow[r]*alpha + rs;
            mrow[r] = mnew;
            pbuf[0][r] = p0; pbuf[1][r] = p1; pbuf[2][r] = p2; pbuf[3][r] = p3;
#pragma unroll
            for (int nt = 0; nt < 4; ++nt) { o1[nt][r] *= alpha; o2[nt][r] *= alpha; }
        }
#pragma unroll
        for (int nt = 0; nt < 4; ++nt)
#pragma unroll
            for (int r = 0; r < 4; ++r) {
                _Float16 h_, l_; fsplit(pbuf[nt][r], h_, l_);
                Ph[w*16 + quad*4 + r][nt*16 + m16] = h_;
                Pl[w*16 + quad*4 + r][nt*16 + m16] = l_;
            }
        __syncthreads();

#pragma unroll
        for (int ks = 0; ks < 2; ++ks) {
            f16x8 ph = *(const f16x8*)&Ph[w*16 + m16][ks*32 + quad*8];
            f16x8 pl = *(const f16x8*)&Pl[w*16 + m16][ks*32 + quad*8];
#pragma unroll
            for (int nt = 0; nt < 4; ++nt) {
                f16x8 vh_ = *(const f16x8*)&Vh[nt*16 + m16][ks*32 + quad*8];
                f16x8 vl_ = *(const f16x8*)&Vl[nt*16 + m16][ks*32 + quad*8];
                o1[nt] = MFMA16(ph, vh_, o1[nt], 0, 0, 0);
                o2[nt] = MFMA16(ph, vl_, o2[nt], 0, 0, 0);
                o2[nt] = MFMA16(pl, vh_, o2[nt], 0, 0, 0);
            }
        }
        __syncthreads();
    }
#pragma unroll
    for (int r = 0; r < 4; ++r) {
        float inv = 1.0f / lrow[r];
        size_t rowp = (bbase + q0 + w*16 + quad*4 + r)*DM + hh*DH;
#pragma unroll
        for (int nt = 0; nt < 4; ++nt) {
            float ov = (o1[nt][r] + o2[nt][r]*ILSC) * inv;
            _Float16 h_, l_; fsplit(ov, h_, l_);
            oh[rowp + nt*16 + m16] = h_;
            ol[rowp + nt*16 + m16] = l_;
        }
    }
}

// ---------------------------------------------------------------- LayerNorm
__global__ __launch_bounds__(256) void ln_kernel(
        _Float16* __restrict__ hhi, _Float16* __restrict__ hlo,
        const float* __restrict__ res,
        const float* __restrict__ w, const float* __restrict__ b) {
    int rowi = blockIdx.x, t = threadIdx.x;
    size_t base = (size_t)rowi * DM;
    float v0 = frec(hhi[base + t], hlo[base + t]);
    float v1 = frec(hhi[base + t + 256], hlo[base + t + 256]);
    if (res) { v0 += res[base + t]; v1 += res[base + t + 256]; }
    __shared__ float rs[256], rq[256];
    rs[t] = v0 + v1; rq[t] = v0*v0 + v1*v1;
    __syncthreads();
    for (int off = 128; off > 0; off >>= 1) {
        if (t < off) { rs[t] += rs[t+off]; rq[t] += rq[t+off]; }
        __syncthreads();
    }
    float m = rs[0] / (float)DM;
    float var = rq[0] / (float)DM - m*m;
    float inv = 1.0f / sqrtf(var + LN_EPS);
    float y0 = (v0 - m)*inv * w[t]       + b[t];
    float y1 = (v1 - m)*inv * w[t + 256] + b[t + 256];
    _Float16 h0, l0, h1, l1;
    fsplit(y0, h0, l0); fsplit(y1, h1, l1);
    hhi[base + t] = h0;       hlo[base + t] = l0;
    hhi[base + t + 256] = h1; hlo[base + t + 256] = l1;
}

__device__ __forceinline__ float gelu_exact(float xv) {
    return 0.5f * xv * (1.0f + erff(xv * 0.70710678118654752f));
}

// ---------------------------------------------------------------- MoE FFN
__global__ __launch_bounds__(256) void moe_kernel(
        const _Float16* __restrict__ hhi, const _Float16* __restrict__ hlo,
        float* __restrict__ out,
        const float* __restrict__ gW, const float* __restrict__ W1, const float* __restrict__ b1,
        const float* __restrict__ W2, const float* __restrict__ b2) {
    int tok = blockIdx.x, t = threadIdx.x;
    __shared__ float hs[DM];
    __shared__ float red[32][8];
    __shared__ float glog[8];
    __shared__ float hmid[8];
    __shared__ float wsel[2];
    __shared__ int   esel[2];
    size_t base = (size_t)tok * DM;
    hs[t] = frec(hhi[base + t], hlo[base + t]);
    hs[t + 256] = frec(hhi[base + t + 256], hlo[base + t + 256]);
    __syncthreads();
    int e = t & 7, i0 = t >> 3;
    {
        float a = 0.f;
        for (int i = i0; i < DM; i += 32) a += hs[i] * gW[i*NE + e];
        red[i0][e] = a;
    }
    __syncthreads();
    if (t < 8) { float sv = 0.f; for (int i = 0; i < 32; ++i) sv += red[i][t]; glog[t] = sv; }
    __syncthreads();
    if (t == 0) {
        float m0 = -1e30f, m1 = -1e30f; int s0i = 0, s1i = 0;
        for (int ei = 0; ei < 8; ++ei) {
            float vv = glog[ei];
            if (vv > m0) { m1 = m0; s1i = s0i; m0 = vv; s0i = ei; }
            else if (vv > m1) { m1 = vv; s1i = ei; }
        }
        float Z = 0.f;
        for (int ei = 0; ei < 8; ++ei) Z += expf(glog[ei] - m0);
        wsel[0] = 1.0f / Z;
        wsel[1] = expf(m1 - m0) / Z;
        esel[0] = s0i; esel[1] = s1i;
    }
    __syncthreads();
    float o0 = 0.f, o1 = 0.f;
    for (int ks = 0; ks < 2; ++ks) {
        int ee = esel[ks]; float wk = wsel[ks];
        int f = t & 7;
        float a = 0.f;
        for (int i = i0; i < DM; i += 32) a += hs[i] * W1[((size_t)ee*DM + i)*NF + f];
        red[i0][f] = a;
        __syncthreads();
        if (t < 8) {
            float sv = b1[ee*NF + t];
            for (int i = 0; i < 32; ++i) sv += red[i][t];
            hmid[t] = gelu_exact(sv);
        }
        __syncthreads();
        float s0v = b2[ee*DM + t], s1v = b2[ee*DM + t + 256];
#pragma unroll
        for (int i = 0; i < NF; ++i) {
            float hm = hmid[i];
            const float* wp = W2 + ((size_t)ee*NF + i)*DM;
            s0v += hm * wp[t]; s1v += hm * wp[t + 256];
        }
        o0 += wk * s0v; o1 += wk * s1v;
        __syncthreads();
    }
    out[base + t] = o0; out[base + t + 256] = o1;
}

// ------------------------------------------------------------- head: init
__global__ __launch_bounds__(64) void head_init_kernel(int* __restrict__ cnt) {
    if (threadIdx.x < NE) cnt[threadIdx.x] = 0;
}

// ------------------------------------------------------------- head: gate
__global__ __launch_bounds__(256) void head_gate_kernel(
        const _Float16* __restrict__ hhi, const _Float16* __restrict__ hlo,
        const float* __restrict__ gW,
        int* __restrict__ sel, float2* __restrict__ wpair) {
    int tok = blockIdx.x, t = threadIdx.x;
    __shared__ float hs[DM];
    __shared__ float red[32][8];
    __shared__ float glog[8];
    size_t base = (size_t)tok * DM;
    hs[t] = frec(hhi[base + t], hlo[base + t]);
    hs[t + 256] = frec(hhi[base + t + 256], hlo[base + t + 256]);
    __syncthreads();
    int e = t & 7, i0 = t >> 3;
    float a = 0.f;
    for (int i = i0; i < DM; i += 32) a += hs[i] * gW[i*NE + e];
    red[i0][e] = a;
    __syncthreads();
    if (t < 8) { float sv = 0.f; for (int i = 0; i < 32; ++i) sv += red[i][t]; glog[t] = sv; }
    __syncthreads();
    if (t == 0) {
        float m0 = -1e30f, m1 = -1e30f; int s0i = 0, s1i = 0;
        for (int ei = 0; ei < 8; ++ei) {
            float vv = glog[ei];
            if (vv > m0) { m1 = m0; s1i = s0i; m0 = vv; s0i = ei; }
            else if (vv > m1) { m1 = vv; s1i = ei; }
        }
        float Z = 0.f;
        for (int ei = 0; ei < 8; ++ei) Z += __expf(glog[ei] - m0);
        float2 wv;
        wv.x = 1.0f / Z;
        wv.y = __expf(m1 - m0) / Z;
        sel[tok] = s0i | (s1i << 3);
        wpair[tok] = wv;
    }
}

// ------------------------------------------------------------- head: bucket
// One wave per 64 tokens; ballot-aggregated inserts: 1 atomic per (wave,expert).
// Also records each token's (expert,pos) encodings for slot lookup.
__global__ __launch_bounds__(64) void head_bucket_kernel(
        const int* __restrict__ sel, const float2* __restrict__ wpair,
        int* __restrict__ cnt, int* __restrict__ idxlist, float* __restrict__ wlist,
        int* __restrict__ pos0, int* __restrict__ pos1) {
    int lane = threadIdx.x;
    int tok = blockIdx.x*64 + lane;
    int s = sel[tok];
    int s0 = s & 7, s1 = (s >> 3) & 7;
    float2 wv = wpair[tok];
    unsigned long long lmask = (lane == 63) ? 0x7FFFFFFFFFFFFFFFull
                                            : ((1ull << lane) - 1ull);
#pragma unroll
    for (int e = 0; e < NE; ++e) {
        unsigned long long m0 = __ballot(s0 == e);
        unsigned long long m1 = __ballot(s1 == e);
        int tot = __popcll(m0) + __popcll(m1);
        int basep = 0;
        if (lane == 0 && tot > 0) basep = atomicAdd(&cnt[e], tot);
        basep = __shfl(basep, 0);
        if (s0 == e) {
            int p = basep + __popcll(m0 & lmask);
            idxlist[e*NTOK + p] = tok; wlist[e*NTOK + p] = wv.x;
            pos0[tok] = (e << 16) | p;
        }
        if (s1 == e) {
            int p = basep + __popcll(m0) + __popcll(m1 & lmask);
            idxlist[e*NTOK + p] = tok; wlist[e*NTOK + p] = wv.y;
            pos1[tok] = (e << 16) | p;
        }
    }
}

// ------------------------------------------------------------- head: prefix
__global__ __launch_bounds__(64) void head_prefix_kernel(int* __restrict__ cnt) {
    if (threadIdx.x == 0) {
        int run = 0;
        for (int e = 0; e < NE; ++e) { cnt[8 + e] = run; run += cnt[e]; }
    }
}

// --------------------------------------------- head: grouped GEMM, fp16x2 MFMA
// block: (n-half x(2), mtile y(64 rows), expert z).  Gathers <=64 token rows,
// computes [64 x 512] @ W_e[512 x 256]^T-slice, writes w*(acc+bias) to slot buf.
__global__ __launch_bounds__(256) void head_gemm_f16x2_kernel(
        const _Float16* __restrict__ hhi, const _Float16* __restrict__ hlo,
        const _Float16* __restrict__ hwhi, const _Float16* __restrict__ hwlo,
        const float* __restrict__ Hb,
        const int* __restrict__ cnt, const int* __restrict__ idxlist,
        const float* __restrict__ wlist, float* __restrict__ slotf) {
    int e = blockIdx.z;
    int cnt_e = cnt[e];
    int m0 = blockIdx.y << 6;
    if (m0 >= cnt_e) return;
    int rv = cnt_e - m0; if (rv > 64) rv = 64;
    int bn = blockIdx.x << 8;            // 0 or 256
    int pref_e = cnt[8 + e];
    int t = threadIdx.x;
    int w = t >> 6, lane = t & 63, m16 = lane & 15, quad = lane >> 4;

    __shared__ _Float16 sAh[64][40], sAl[64][40];
    __shared__ _Float16 sBh[256][40], sBl[256][40];
    __shared__ int   idxs[64];
    __shared__ float ws[64];
    if (t < 64) {
        if (t < rv) { idxs[t] = idxlist[e*NTOK + m0 + t]; ws[t] = wlist[e*NTOK + m0 + t]; }
        else        { idxs[t] = idxlist[e*NTOK + m0];     ws[t] = 0.f; }
    }
    __syncthreads();

    const _Float16* Wh = hwhi + (size_t)e*DM*DM;
    const _Float16* Wl = hwlo + (size_t)e*DM*DM;
    int ra = t >> 2, ca = (t & 3) << 3;   // A: 64 rows x 4 groups of 8
    f32x4 a1[4][4] = {}, a2[4][4] = {};   // [mtile][ntile]
    for (int k0 = 0; k0 < DM; k0 += 32) {
        size_t ga = (size_t)idxs[ra]*DM + k0 + ca;
        *(uint4*)&sAh[ra][ca] = *(const uint4*)&hhi[ga];
        *(uint4*)&sAl[ra][ca] = *(const uint4*)&hlo[ga];
        size_t gb = (size_t)(bn + t)*DM + k0;
#pragma unroll
        for (int j = 0; j < 4; ++j) {
            *(uint4*)&sBh[t][j*8] = *(const uint4*)&Wh[gb + j*8];
            *(uint4*)&sBl[t][j*8] = *(const uint4*)&Wl[gb + j*8];
        }
        __syncthreads();
        f16x8 ah[4], al[4];
#pragma unroll
        for (int mt = 0; mt < 4; ++mt) {
            ah[mt] = *(const f16x8*)&sAh[mt*16 + m16][quad*8];
            al[mt] = *(const f16x8*)&sAl[mt*16 + m16][quad*8];
        }
#pragma unroll
        for (int nt = 0; nt < 4; ++nt) {
            f16x8 bh_ = *(const f16x8*)&sBh[w*64 + nt*16 + m16][quad*8];
            f16x8 bl_ = *(const f16x8*)&sBl[w*64 + nt*16 + m16][quad*8];
#pragma unroll
            for (int mt = 0; mt < 4; ++mt) {
                a1[mt][nt] = MFMA16(ah[mt], bh_, a1[mt][nt], 0, 0, 0);
                a2[mt][nt] = MFMA16(ah[mt], bl_, a2[mt][nt], 0, 0, 0);
                a2[mt][nt] = MFMA16(al[mt], bh_, a2[mt][nt], 0, 0, 0);
            }
        }
        __syncthreads();
    }
#pragma unroll
    for (int mt = 0; mt < 4; ++mt)
#pragma unroll
        for (int r = 0; r < 4; ++r) {
            int rloc = mt*16 + quad*4 + r;
            if (rloc < rv) {
                float wk = ws[rloc];
                size_t srow = (size_t)(pref_e + m0 + rloc)*DM;
#pragma unroll
                for (int nt = 0; nt < 4; ++nt) {
                    int gcol = bn + w*64 + nt*16 + m16;
                    float v = a1[mt][nt][r] + a2[mt][nt][r]*ILSC + Hb[e*DM + gcol];
                    slotf[srow + gcol] = wk * v;
                }
            }
        }
}

// ------------------------------------------------------------- head: combine+denorm
__global__ __launch_bounds__(256) void head_combine_kernel(
        const float* __restrict__ slotf,
        const int* __restrict__ pos0, const int* __restrict__ pos1,
        const int* __restrict__ cnt,
        const float* __restrict__ rw, const float* __restrict__ rb,
        const float* __restrict__ mean, const float* __restrict__ stdd,
        float* __restrict__ out) {
    int tok = blockIdx.x, t = threadIdx.x;
    int n = tok & (NVAR - 1);
    int e0enc = pos0[tok], e1enc = pos1[tok];
    size_t s0 = (size_t)(cnt[8 + (e0enc >> 16)] + (e0enc & 0xFFFF)) * DM;
    size_t s1 = (size_t)(cnt[8 + (e1enc >> 16)] + (e1enc & 0xFFFF)) * DM;
    size_t base = (size_t)tok * DM;
    float mn = mean[tok], sd = stdd[tok];
    float rwv = rw[n] + 1e-10f, rbv = rb[n];
    float o0 = slotf[s0 + t] + slotf[s1 + t];
    float o1 = slotf[s0 + t + 256] + slotf[s1 + t + 256];
    out[base + t]       = (o0 - rbv) / rwv * sd + mn;
    out[base + t + 256] = (o1 - rbv) / rwv * sd + mn;
}

// ---------------------------------------------------------------- launch
extern "C" void kernel_launch(void* const* d_in, const int* in_sizes, int n_in,
                              void* d_out, int out_size, void* d_ws, size_t ws_size,
                              hipStream_t stream) {
    const float* x       = (const float*)d_in[0];
    const float* revin_w = (const float*)d_in[1];
    const float* revin_b = (const float*)d_in[2];
    const float* emb_W   = (const float*)d_in[3];
    const float* emb_b   = (const float*)d_in[4];
    const float* Wq      = (const float*)d_in[5];
    const float* bq      = (const float*)d_in[6];
    const float* Wk      = (const float*)d_in[7];
    const float* bk      = (const float*)d_in[8];
    const float* Wv      = (const float*)d_in[9];
    const float* bv      = (const float*)d_in[10];
    const float* Wo      = (const float*)d_in[11];
    const float* bo      = (const float*)d_in[12];
    const float* ln1_w   = (const float*)d_in[13];
    const float* ln1_b   = (const float*)d_in[14];
    const float* ln2_w   = (const float*)d_in[15];
    const float* ln2_b   = (const float*)d_in[16];
    const float* gate_W  = (const float*)d_in[17];
    const float* eW1     = (const float*)d_in[18];
    const float* eb1     = (const float*)d_in[19];
    const float* eW2     = (const float*)d_in[20];
    const float* eb2     = (const float*)d_in[21];
    const float* enc_w   = (const float*)d_in[22];
    const float* enc_b   = (const float*)d_in[23];
    const float* hgW     = (const float*)d_in[24];
    const float* hW      = (const float*)d_in[25];
    const float* hb      = (const float*)d_in[26];
    float* out = (float*)d_out;

    const size_t TOKD = (size_t)NTOK * DM;   // 4194304
    float* ws   = (float*)d_ws;
    float* mean = ws;
    float* stdd = ws + 8192;
    _Float16* hhi  = (_Float16*)(ws + 16384);
    _Float16* hlo  = hhi + TOKD;
    _Float16* qhi  = hlo + TOKD;     // head stage: slotf spans qhi..klo (32 MiB)
    _Float16* qlo  = qhi + TOKD;
    _Float16* khi  = qlo + TOKD;     // also proj fp32 raw
    _Float16* klo  = khi + TOKD;
    _Float16* vthi = klo + TOKD;     // head stage: head split weights (4 MB used)
    _Float16* vtlo = vthi + TOKD;
    _Float16* whi  = vtlo + TOKD;    // 9 transposed split weights
    _Float16* wlo  = whi + (size_t)9*DM*DM;
    int*   cnt     = (int*)(wlo + (size_t)9*DM*DM);   // [0..7]=cnt, [8..15]=prefix
    int*   idxlist = cnt + 16;
    float* wlist   = (float*)(idxlist + NE*NTOK);
    int*   sel     = (int*)(wlist + NE*NTOK);
    float2* wpair  = (float2*)(sel + NTOK);
    int*   pos0    = (int*)(wpair + NTOK);
    int*   pos1    = pos0 + NTOK;
    float* proj    = (float*)khi;
    float* slotf   = (float*)qhi;

    dim3 blk(256);
    dim3 ggemm(DM/64, NTOK/128);     // (8, 64)

    revin_stats_kernel<<<dim3(BATCH*16), blk, 0, stream>>>(x, mean, stdd);
    revin_norm_kernel<<<dim3(NVAR/32, SEQ/32, BATCH), blk, 0, stream>>>(
        x, mean, stdd, revin_w, revin_b, qhi, qlo);

    WSrcs srcs;
    srcs.p[0] = emb_W;
    for (int l = 0; l < NL; ++l) {
        srcs.p[1 + l*4 + 0] = Wq + (size_t)l*DM*DM;
        srcs.p[1 + l*4 + 1] = Wk + (size_t)l*DM*DM;
        srcs.p[1 + l*4 + 2] = Wv + (size_t)l*DM*DM;
        srcs.p[1 + l*4 + 3] = Wo + (size_t)l*DM*DM;
    }
    transpose_w_kernel<<<dim3(8, 8, 9), blk, 0, stream>>>(srcs, whi, wlo);

    gemm_f16x2_kernel<<<ggemm, blk, 0, stream>>>(
        qhi, qlo, whi, wlo, emb_b, nullptr, hhi, hlo, NTOK, SEQ, DM);

    for (int l = 0; l < NL; ++l) {
        size_t oq = (size_t)(1 + l*4 + 0)*DM*DM;
        size_t ok = (size_t)(1 + l*4 + 1)*DM*DM;
        size_t ov = (size_t)(1 + l*4 + 2)*DM*DM;
        size_t oo = (size_t)(1 + l*4 + 3)*DM*DM;
        gemm_f16x2_kernel<<<ggemm, blk, 0, stream>>>(
            hhi, hlo, whi + oq, wlo + oq, bq + l*DM, nullptr, qhi, qlo, NTOK, DM, DM);
        gemm_f16x2_kernel<<<ggemm, blk, 0, stream>>>(
            hhi, hlo, whi + ok, wlo + ok, bk + l*DM, nullptr, khi, klo, NTOK, DM, DM);
        gemm_f16x2_vt_kernel<<<ggemm, blk, 0, stream>>>(
            hhi, hlo, whi + ov, wlo + ov, bv + l*DM, vthi, vtlo);
        attn_f16x2_kernel<<<dim3(64*16), blk, 0, stream>>>(
            qhi, qlo, khi, klo, vthi, vtlo, qhi, qlo);
        gemm_f16x2_kernel<<<ggemm, blk, 0, stream>>>(
            qhi, qlo, whi + oo, wlo + oo, bo + l*DM, proj, nullptr, nullptr, NTOK, DM, DM);
        ln_kernel<<<dim3(NTOK), blk, 0, stream>>>(hhi, hlo, proj, ln1_w + l*DM, ln1_b + l*DM);
        moe_kernel<<<dim3(NTOK), blk, 0, stream>>>(
            hhi, hlo, proj, gate_W + (size_t)l*DM*NE,
            eW1 + (size_t)l*NE*DM*NF, eb1 + (size_t)l*NE*NF,
            eW2 + (size_t)l*NE*NF*DM, eb2 + (size_t)l*NE*DM);
        ln_kernel<<<dim3(NTOK), blk, 0, stream>>>(hhi, hlo, proj, ln2_w + l*DM, ln2_b + l*DM);
    }

    ln_kernel<<<dim3(NTOK), blk, 0, stream>>>(hhi, hlo, nullptr, enc_w, enc_b);

    // head expert weights -> split f16 in the (now dead) vt planes
    WSrcs hsrcs;
    for (int e = 0; e < NE; ++e) hsrcs.p[e] = hW + (size_t)e*DM*DM;
    hsrcs.p[8] = hW;   // unused
    transpose_w_kernel<<<dim3(8, 8, 8), blk, 0, stream>>>(hsrcs, vthi, vtlo);

    head_init_kernel<<<dim3(1), dim3(64), 0, stream>>>(cnt);
    head_gate_kernel<<<dim3(NTOK), blk, 0, stream>>>(hhi, hlo, hgW, sel, wpair);
    head_bucket_kernel<<<dim3(NTOK/64), dim3(64), 0, stream>>>(
        sel, wpair, cnt, idxlist, wlist, pos0, pos1);
    head_prefix_kernel<<<dim3(1), dim3(64), 0, stream>>>(cnt);
    head_gemm_f16x2_kernel<<<dim3(2, NTOK/64, NE), blk, 0, stream>>>(
        hhi, hlo, vthi, vtlo, hb, cnt, idxlist, wlist, slotf);
    head_combine_kernel<<<dim3(NTOK), blk, 0, stream>>>(
        slotf, pos0, pos1, cnt, revin_w, revin_b, mean, stdd, out);
}